// Round 16
// baseline (6705.543 us; speedup 1.0000x reference)
//
#include <hip/hip_runtime.h>

#define DEVI static __device__ __forceinline__

typedef float    f32x4 __attribute__((ext_vector_type(4)));
typedef _Float16 f16x8 __attribute__((ext_vector_type(8)));

static constexpr int Bn = 8, Ln = 4096, Dn = 1024, Hn = 16, DKn = 64;
static constexpr int TOPK = 8;
static constexpr float LO_SCALE = 2048.f, LO_INV = 1.f / 2048.f;

DEVI f32x4 mfma_f16(f16x8 a, f16x8 b, f32x4 c) {
    return __builtin_amdgcn_mfma_f32_16x16x32_f16(a, b, c, 0, 0, 0);
}

struct HL { _Float16 hi, lo; };
DEVI HL split2(float x) {
    HL r;
    r.hi = (_Float16)x;
    r.lo = (_Float16)((x - (float)r.hi) * LO_SCALE);
    return r;
}

DEVI void gload16(const void* g, void* l) {
    __builtin_amdgcn_global_load_lds(
        (const __attribute__((address_space(1))) unsigned int*)g,
        (__attribute__((address_space(3))) unsigned int*)l,
        16, 0, 0);
}

// ---------------------------------------------------------------------------
// conversion kernels (memory-bound)
// ---------------------------------------------------------------------------
__global__ __launch_bounds__(256) void cvt_split_k(
    const float* __restrict__ srcA, _Float16* __restrict__ hiA, _Float16* __restrict__ loA,
    const float* __restrict__ srcB, _Float16* __restrict__ hiB, _Float16* __restrict__ loB,
    int n8)
{
    const float* s  = blockIdx.y ? srcB : srcA;
    _Float16*    ph = blockIdx.y ? hiB  : hiA;
    _Float16*    pl = blockIdx.y ? loB  : loA;
    const int idx = blockIdx.x * 256 + threadIdx.x;
    if (idx >= n8) return;
    f32x4 x0 = *(const f32x4*)(s + (size_t)idx * 8);
    f32x4 x1 = *(const f32x4*)(s + (size_t)idx * 8 + 4);
    f16x8 h, l;
#pragma unroll
    for (int j = 0; j < 4; j++) {
        HL p0 = split2(x0[j]), p1 = split2(x1[j]);
        h[j] = p0.hi; l[j] = p0.lo;
        h[4 + j] = p1.hi; l[4 + j] = p1.lo;
    }
    *(f16x8*)(ph + (size_t)idx * 8) = h;
    *(f16x8*)(pl + (size_t)idx * 8) = l;
}

__global__ __launch_bounds__(256) void cvt_f16_k(
    const float* __restrict__ srcA, _Float16* __restrict__ dstA,
    const float* __restrict__ srcB, _Float16* __restrict__ dstB, int n8)
{
    const float* s = blockIdx.y ? srcB : srcA;
    _Float16*    d = blockIdx.y ? dstB : dstA;
    const int idx = blockIdx.x * 256 + threadIdx.x;
    if (idx >= n8) return;
    f32x4 x0 = *(const f32x4*)(s + (size_t)idx * 8);
    f32x4 x1 = *(const f32x4*)(s + (size_t)idx * 8 + 4);
    f16x8 o;
#pragma unroll
    for (int j = 0; j < 4; j++) { o[j] = (_Float16)x0[j]; o[4 + j] = (_Float16)x1[j]; }
    *(f16x8*)(d + (size_t)idx * 8) = o;
}

// ---------------------------------------------------------------------------
// m97-structure GEMM: C[m,n] = sum_k A[m,k]*W[n,k] + bias[n], K = 1024.
// 128x128 tile, BK=32, 4 waves, global_load_lds staging, 2-barrier K-loop.
// COMP: A and W in hi + scaled-lo f16 pairs; 3-term compensated MFMA.
// AF32: A staged raw f32 (swizzled source), cast at fragment load (gemm_v).
// MODE 0: out0 f32 row-major [M][1024]                  (final O-proj)
// MODE 1: out0 f16 head-split [b][h][l][64], b=m>>12    (V staging)
// MODE 2: out0 f32 TRANSPOSED [b2][n][l] via LDS-transpose epilogue,
//         coalesced 512B-row stores                     (Q/K for FFT corr)
// ---------------------------------------------------------------------------
DEVI void stage8(const _Float16* gbase, _Float16* ltile, int w, int lane, int k0) {
#pragma unroll
    for (int c = 0; c < 2; c++) {
        const int chunk = 2 * w + c;
        const int row = chunk * 16 + (lane >> 2);
        gload16(gbase + (size_t)row * Dn + k0 + (lane & 3) * 8, ltile + chunk * 512);
    }
}

DEVI void stage16f32(const float* gbase, float* ltile, int w, int lane, int k0) {
    const int r    = lane >> 3;
    const int gsrc = (lane & 7) ^ r;
#pragma unroll
    for (int c = 0; c < 4; c++) {
        const int chunk = w * 4 + c;
        const int row = chunk * 8 + r;
        gload16(gbase + (size_t)row * Dn + k0 + gsrc * 4, ltile + chunk * 256);
    }
}

template<int MODE, bool COMP, bool AF32>
DEVI void gemm4_body(
    const void* __restrict__ A_hi, const _Float16* __restrict__ A_lo,
    const _Float16* __restrict__ W_hi, const _Float16* __restrict__ W_lo,
    const float* __restrict__ bias, void* __restrict__ out0)
{
    // A region: AF32 -> 16KB f32; COMP -> 8KB hi + 8KB lo; else 8KB.
    constexpr int ASZ = (AF32 || COMP) ? 16384 : 8192;
    __shared__ char smem[ASZ + (COMP ? 16384 : 8192)];
    float*    sAf = (float*)smem;
    _Float16* sAh = (_Float16*)smem;
    _Float16* sAl = (_Float16*)(smem + 8192);      // COMP only
    _Float16* sWh = (_Float16*)(smem + ASZ);
    _Float16* sWl = (_Float16*)(smem + ASZ + 8192);

    const int l  = threadIdx.x & 63;
    const int w  = threadIdx.x >> 6;
    const int m0 = blockIdx.x * 128;
    const int n0 = blockIdx.y * 128;
    const int wm = (w & 1) * 64, wn = (w >> 1) * 64;
    const int rr = l & 15, ko = (l >> 4) * 8, g0 = (l >> 4) * 2;

    const _Float16* Wbh = W_hi + (size_t)n0 * Dn;
    const _Float16* Wbl = COMP ? W_lo + (size_t)n0 * Dn : nullptr;

    f32x4 acc[4][4] = {};
    f32x4 accc[4][4] = {};

    for (int k0 = 0; k0 < Dn; k0 += 32) {
        if (AF32) {
            stage16f32((const float*)A_hi + (size_t)m0 * Dn, sAf, w, l, k0);
        } else {
            stage8((const _Float16*)A_hi + (size_t)m0 * Dn, sAh, w, l, k0);
            if (COMP) stage8(A_lo + (size_t)m0 * Dn, sAl, w, l, k0);
        }
        stage8(Wbh, sWh, w, l, k0);
        if (COMP) stage8(Wbl, sWl, w, l, k0);
        __syncthreads();

        f16x8 af[4], alf[4], bf[4], blf[4];
#pragma unroll
        for (int i = 0; i < 4; i++) {
            const int arow = wm + 16 * i + rr;
            if (AF32) {
                const float* rb = &sAf[arow * 32];
                f32x4 x0 = *(const f32x4*)&rb[((g0    ) ^ (arow & 7)) * 4];
                f32x4 x1 = *(const f32x4*)&rb[((g0 + 1) ^ (arow & 7)) * 4];
#pragma unroll
                for (int j = 0; j < 4; j++) {
                    af[i][j]     = (_Float16)x0[j];
                    af[i][4 + j] = (_Float16)x1[j];
                }
            } else {
                af[i] = *(const f16x8*)&sAh[arow * 32 + ko];
                if (COMP) alf[i] = *(const f16x8*)&sAl[arow * 32 + ko];
            }
            bf[i] = *(const f16x8*)&sWh[(wn + 16 * i + rr) * 32 + ko];
            if (COMP) blf[i] = *(const f16x8*)&sWl[(wn + 16 * i + rr) * 32 + ko];
        }
#pragma unroll
        for (int i = 0; i < 4; i++)
#pragma unroll
            for (int j = 0; j < 4; j++) {
                acc[i][j] = mfma_f16(af[i], bf[j], acc[i][j]);
                if (COMP) {
                    accc[i][j] = mfma_f16(alf[i], bf[j], accc[i][j]);
                    accc[i][j] = mfma_f16(af[i], blf[j], accc[i][j]);
                }
            }
        __syncthreads();
    }

    if (MODE == 2) {
        // LDS-transpose epilogue: coalesced stores to [b2][n][l] f32.
        float* sT = (float*)smem;          // 32 x 132 f32 (16.9KB, smem free)
        const int b2 = m0 >> 12;
        const int mb = m0 & (Ln - 1);
        const int npr = (wn >> 6) * 16 + rr;           // n' in [0,32)
#pragma unroll 1
        for (int j = 0; j < 4; j++) {
            __syncthreads();
            const float bs = bias[n0 + wn + 16 * j + rr];
#pragma unroll
            for (int i = 0; i < 4; i++)
#pragma unroll
                for (int r = 0; r < 4; r++) {
                    float v = acc[i][j][r] + accc[i][j][r] * LO_INV + bs;
                    sT[npr * 132 + wm + 16 * i + (l >> 4) * 4 + r] = v;
                }
            __syncthreads();
            const int row = threadIdx.x >> 3;          // [0,32)
            const int cb  = (threadIdx.x & 7) * 16;
            const int n   = n0 + (row >> 4) * 64 + 16 * j + (row & 15);
            float* dst = (float*)out0 + ((size_t)(b2 * 1024 + n)) * Ln + mb + cb;
            const float* sp = &sT[row * 132 + cb];
#pragma unroll
            for (int c4 = 0; c4 < 4; c4++)
                *(f32x4*)(dst + 4 * c4) = *(const f32x4*)(sp + 4 * c4);
        }
        return;
    }

#pragma unroll
    for (int i = 0; i < 4; i++)
#pragma unroll
        for (int j = 0; j < 4; j++)
#pragma unroll
            for (int r = 0; r < 4; r++) {
                const int m = m0 + wm + 16 * i + (l >> 4) * 4 + r;
                const int n = n0 + wn + 16 * j + (l & 15);
                float v = acc[i][j][r] + bias[n];
                if (MODE == 0) {
                    ((float*)out0)[(size_t)m * Dn + n] = v;
                } else {
                    size_t idx = ((size_t)((m >> 12) * Hn + (n >> 6)) * Ln
                                  + (m & (Ln - 1))) * DKn + (n & 63);
                    ((_Float16*)out0)[idx] = (_Float16)v;
                }
            }
}

__global__ __launch_bounds__(256) void gemm_v_k(
    const float* __restrict__ xv, const _Float16* __restrict__ Wv,
    const float* __restrict__ bv, _Float16* __restrict__ Vstage)
{
    gemm4_body<1, false, true>(xv, nullptr, Wv, nullptr, bv, Vstage);
}

__global__ __launch_bounds__(256) void gemm_o_k(
    const _Float16* __restrict__ Y, const _Float16* __restrict__ Wo,
    const float* __restrict__ bo, float* __restrict__ out)
{
    gemm4_body<0, false, false>(Y, nullptr, Wo, nullptr, bo, out);
}

// 2 batches per launch (M=8192); z=0 -> Q, z=1 -> K. Pre-split f16 inputs.
__global__ __launch_bounds__(256) void gemm_qk_k(
    const _Float16* __restrict__ xqhi, const _Float16* __restrict__ xqlo,
    const _Float16* __restrict__ xkhi, const _Float16* __restrict__ xklo,
    const _Float16* __restrict__ Wqhi, const _Float16* __restrict__ Wqlo,
    const _Float16* __restrict__ Wkhi, const _Float16* __restrict__ Wklo,
    const float* __restrict__ bq, const float* __restrict__ bk,
    float* __restrict__ QT, float* __restrict__ KT)
{
    if (blockIdx.z == 0)
        gemm4_body<2, true, false>(xqhi, xqlo, Wqhi, Wqlo, bq, QT);
    else
        gemm4_body<2, true, false>(xkhi, xklo, Wkhi, Wklo, bk, KT);
}

// ---------------------------------------------------------------------------
// FFT-based correlation (unchanged from round 14, verified).
// ---------------------------------------------------------------------------
DEVI int FPAD(int i) { return i + (i >> 4); }

DEVI float2 cmulf(float2 a, float2 b) {
    return make_float2(a.x * b.x - a.y * b.y, a.x * b.y + a.y * b.x);
}

DEVI void fft_pass(const float2* in, float2* out, int ls2, int tid) {
    const int Ns = 1 << ls2;
#pragma unroll
    for (int r = 0; r < 4; r++) {
        const int j = tid + r * 256;
        float2 v0 = in[FPAD(j)];
        float2 v1 = in[FPAD(j + 1024)];
        float2 v2 = in[FPAD(j + 2048)];
        float2 v3 = in[FPAD(j + 3072)];
        const int p = j & (Ns - 1);
        const float ang = -6.283185307179586f * (float)p / (4.f * (float)Ns);
        float sn, cs;
        __sincosf(ang, &sn, &cs);
        const float2 w1 = make_float2(cs, sn);
        const float2 w2 = cmulf(w1, w1);
        const float2 w3 = cmulf(w2, w1);
        v1 = cmulf(v1, w1); v2 = cmulf(v2, w2); v3 = cmulf(v3, w3);
        const float2 t0 = make_float2(v0.x + v2.x, v0.y + v2.y);
        const float2 t1 = make_float2(v0.x - v2.x, v0.y - v2.y);
        const float2 t2 = make_float2(v1.x + v3.x, v1.y + v3.y);
        const float2 t3 = make_float2(v1.x - v3.x, v1.y - v3.y);
        const float2 t3i = make_float2(t3.y, -t3.x);
        const int db = ((j >> ls2) << (ls2 + 2)) | p;
        out[FPAD(db)]          = make_float2(t0.x + t2.x, t0.y + t2.y);
        out[FPAD(db + Ns)]     = make_float2(t1.x + t3i.x, t1.y + t3i.y);
        out[FPAD(db + 2 * Ns)] = make_float2(t0.x - t2.x, t0.y - t2.y);
        out[FPAD(db + 3 * Ns)] = make_float2(t1.x - t3i.x, t1.y - t3i.y);
    }
}

DEVI void fft4096(float2* A, float2* B, int tid) {
    __syncthreads();
    fft_pass(A, B, 0, tid);  __syncthreads();
    fft_pass(B, A, 2, tid);  __syncthreads();
    fft_pass(A, B, 4, tid);  __syncthreads();
    fft_pass(B, A, 6, tid);  __syncthreads();
    fft_pass(A, B, 8, tid);  __syncthreads();
    fft_pass(B, A, 10, tid); __syncthreads();
}

__global__ __launch_bounds__(256) void fftcorr_k(
    const float* __restrict__ QT, const float* __restrict__ KT,
    float2* __restrict__ Pf)
{
    __shared__ float2 A[4352], B[4352];
    const int tid = threadIdx.x;
    const int bh  = blockIdx.y;
    const int d0  = blockIdx.x * 4;
    float2 acc[16];
#pragma unroll
    for (int i = 0; i < 16; i++) acc[i] = make_float2(0.f, 0.f);
    float2 qf[16];

    for (int dd = 0; dd < 4; dd++) {
        const int d = d0 + dd;
        const float* qc = QT + ((size_t)bh * 64 + d) * Ln;
        const float* kc = KT + ((size_t)bh * 64 + d) * Ln;
#pragma unroll
        for (int i = 0; i < 16; i++) {
            const int row = tid + 256 * i;
            A[FPAD(row)] = make_float2(qc[row], 0.f);
        }
        fft4096(A, B, tid);
#pragma unroll
        for (int i = 0; i < 16; i++) qf[i] = A[FPAD(tid + 256 * i)];
        __syncthreads();
#pragma unroll
        for (int i = 0; i < 16; i++) {
            const int row = tid + 256 * i;
            A[FPAD(row)] = make_float2(kc[row], 0.f);
        }
        fft4096(A, B, tid);
#pragma unroll
        for (int i = 0; i < 16; i++) {
            float2 kf = A[FPAD(tid + 256 * i)];
            acc[i].x += qf[i].x * kf.x + qf[i].y * kf.y;
            acc[i].y += qf[i].y * kf.x - qf[i].x * kf.y;
        }
        __syncthreads();
    }
    float2* P = Pf + (size_t)bh * Ln;
#pragma unroll
    for (int i = 0; i < 16; i++) {
        atomicAdd(&P[tid + 256 * i].x, acc[i].x);
        atomicAdd(&P[tid + 256 * i].y, acc[i].y);
    }
}

__global__ __launch_bounds__(256) void ifftcorr_k(
    const float2* __restrict__ Pf, float* __restrict__ corr)
{
    __shared__ float2 A[4352], B[4352];
    const int tid = threadIdx.x;
    const int bh = blockIdx.x;
    const float2* P = Pf + (size_t)bh * Ln;
#pragma unroll
    for (int i = 0; i < 16; i++) {
        float2 v = P[tid + 256 * i];
        A[FPAD(tid + 256 * i)] = make_float2(v.x, -v.y);
    }
    fft4096(A, B, tid);
#pragma unroll
    for (int i = 0; i < 16; i++)
        corr[(size_t)bh * Ln + tid + 256 * i] =
            A[FPAD(tid + 256 * i)].x * (1.f / 4096.f);
}

// ---------------------------------------------------------------------------
// Top-8 + softmax per (b,h) row of corr (raw sums; /64 before softmax).
// ---------------------------------------------------------------------------
__global__ __launch_bounds__(256) void topk_k(
    const float* __restrict__ corr, float* __restrict__ top_w,
    int* __restrict__ top_idx)
{
    __shared__ float vals[Ln];
    __shared__ float rv[256];
    __shared__ int   ri[256];
    __shared__ float sel_v[TOPK];
    __shared__ int   sel_i[TOPK];
    const int bh = blockIdx.x;
    const float* c = corr + (size_t)bh * Ln;
    for (int i = threadIdx.x; i < Ln; i += 256) vals[i] = c[i];
    __syncthreads();

    for (int it = 0; it < TOPK; it++) {
        float bvv = -1e30f; int bi = 0;
        const int base = threadIdx.x * 16;
#pragma unroll
        for (int j = 0; j < 16; j++) {
            float v = vals[base + j];
            if (v > bvv) { bvv = v; bi = base + j; }
        }
        rv[threadIdx.x] = bvv; ri[threadIdx.x] = bi;
        __syncthreads();
        if (threadIdx.x == 0) {
            float gv = rv[0]; int gi = ri[0];
            for (int t = 1; t < 256; t++)
                if (rv[t] > gv) { gv = rv[t]; gi = ri[t]; }
            sel_v[it] = gv; sel_i[it] = gi;
            vals[gi] = -1e30f;
        }
        __syncthreads();
    }
    if (threadIdx.x == 0) {
        float e[TOPK], s = 0.f;
        for (int i = 0; i < TOPK; i++) {
            e[i] = expf((sel_v[i] - sel_v[0]) * (1.f / 64.f));
            s += e[i];
        }
        for (int i = 0; i < TOPK; i++) {
            top_w[bh * TOPK + i]   = e[i] / s;
            top_idx[bh * TOPK + i] = sel_i[i];
        }
    }
}

// ---------------------------------------------------------------------------
// Aggregation: Y[b][t][h*64+d] = sum_i w_i * V[b][h][(t-idx_i)&4095][d]
// ---------------------------------------------------------------------------
__global__ __launch_bounds__(256) void agg_k(
    const _Float16* __restrict__ V /* [B][H][L][64] */,
    const float* __restrict__ top_w, const int* __restrict__ top_idx,
    _Float16* __restrict__ Y /* [B][L][1024] */)
{
    __shared__ float w_s[TOPK];
    __shared__ int   i_s[TOPK];
    const int bh   = blockIdx.y;
    const int b    = bh >> 4, h = bh & 15;
    const int tloc = threadIdx.x >> 2;
    const int c16  = (threadIdx.x & 3) * 16;
    const int t    = blockIdx.x * 64 + tloc;
    if (threadIdx.x < TOPK) {
        w_s[threadIdx.x] = top_w[bh * TOPK + threadIdx.x];
        i_s[threadIdx.x] = top_idx[bh * TOPK + threadIdx.x];
    }
    __syncthreads();

    const _Float16* Vb = V + (size_t)bh * Ln * DKn;
    float acc[16] = {};
#pragma unroll
    for (int i = 0; i < TOPK; i++) {
        const int src = (t - i_s[i]) & (Ln - 1);
        const _Float16* p = Vb + (size_t)src * DKn + c16;
        f16x8 v0 = *(const f16x8*)(p);
        f16x8 v1 = *(const f16x8*)(p + 8);
        const float wgt = w_s[i];
#pragma unroll
        for (int j = 0; j < 8; j++) acc[j]     += wgt * (float)v0[j];
#pragma unroll
        for (int j = 0; j < 8; j++) acc[8 + j] += wgt * (float)v1[j];
    }
    f16x8 o0, o1;
#pragma unroll
    for (int j = 0; j < 8; j++) { o0[j] = (_Float16)acc[j]; o1[j] = (_Float16)acc[8 + j]; }
    const size_t oidx = ((size_t)(b * Ln + t)) * Dn + h * DKn + c16;
    *(f16x8*)(Y + oidx)     = o0;
    *(f16x8*)(Y + oidx + 8) = o1;
}

// ---------------------------------------------------------------------------
extern "C" void kernel_launch(void* const* d_in, const int* in_sizes, int n_in,
                              void* d_out, int out_size, void* d_ws, size_t ws_size,
                              hipStream_t stream)
{
    const float* q  = (const float*)d_in[0];
    const float* kk = (const float*)d_in[1];
    const float* v  = (const float*)d_in[2];
    const float* Wq = (const float*)d_in[3];
    const float* bq = (const float*)d_in[4];
    const float* Wk = (const float*)d_in[5];
    const float* bk = (const float*)d_in[6];
    const float* Wv = (const float*)d_in[7];
    const float* bv = (const float*)d_in[8];
    const float* Wo = (const float*)d_in[9];
    const float* bo = (const float*)d_in[10];
    float* out = (float*)d_out;

    // ws layout (bytes), as round 14:
    //   QT f32 [2][1024][4096] @0 ; KT @33554432 ; Y overlays @0 after loop
    //   corr @67108864 ; topw @69206016 ; topi @69210112
    //   Wqhi @69214208 ; Wqlo @71311360 ; Wkhi @73408512 ; Wklo @75505664
    //   Wvf @77602816 ; Wof @79699968 ; Pf cf32[128][4096] @81797120
    char* ws = (char*)d_ws;
    if (ws_size < 85991424ull) return;
    float*    QT   = (float*)(ws);
    float*    KT   = (float*)(ws + 33554432);
    _Float16* Y    = (_Float16*)(ws);
    float*    corr = (float*)(ws + 67108864);
    float*    topw = (float*)(ws + 69206016);
    int*      topi = (int*)(ws + 69210112);
    _Float16* Wqhi = (_Float16*)(ws + 69214208);
    _Float16* Wqlo = (_Float16*)(ws + 71311360);
    _Float16* Wkhi = (_Float16*)(ws + 73408512);
    _Float16* Wklo = (_Float16*)(ws + 75505664);
    _Float16* Wvf  = (_Float16*)(ws + 77602816);
    _Float16* Wof  = (_Float16*)(ws + 79699968);
    float2*   Pf   = (float2*)(ws + 81797120);

    // d_out (128MiB): Vstage f16 [8][16][4096][64] @0 (64MiB);
    // upper 64MiB = per-pair x-split scratch (4 x 16MiB f16 [2][4096][1024]).
    _Float16* Vstage = (_Float16*)d_out;
    _Float16* xqhi = (_Float16*)((char*)d_out + 67108864);
    _Float16* xqlo = (_Float16*)((char*)d_out + 83886080);
    _Float16* xkhi = (_Float16*)((char*)d_out + 100663296);
    _Float16* xklo = (_Float16*)((char*)d_out + 117440512);

    (void)hipMemsetAsync(Pf, 0, (size_t)128 * Ln * sizeof(float2), stream);

    cvt_split_k<<<dim3(512, 2), 256, 0, stream>>>(Wq, Wqhi, Wqlo, Wk, Wkhi, Wklo, 131072);
    cvt_f16_k<<<dim3(512, 2), 256, 0, stream>>>(Wv, Wvf, Wo, Wof, 131072);

    gemm_v_k<<<dim3(256, 8), 256, 0, stream>>>(v, Wvf, bv, Vstage);

    for (int p = 0; p < 4; p++) {
        cvt_split_k<<<dim3(4096, 2), 256, 0, stream>>>(
            q + (size_t)p * 2 * Ln * Dn, xqhi, xqlo,
            kk + (size_t)p * 2 * Ln * Dn, xkhi, xklo, 1048576);
        gemm_qk_k<<<dim3(64, 8, 2), 256, 0, stream>>>(
            xqhi, xqlo, xkhi, xklo,
            Wqhi, Wqlo, Wkhi, Wklo, bq, bk, QT, KT);
        fftcorr_k<<<dim3(16, 32), 256, 0, stream>>>(QT, KT, Pf + (size_t)p * 32 * Ln);
    }
    ifftcorr_k<<<128, 256, 0, stream>>>(Pf, corr);
    topk_k<<<128, 256, 0, stream>>>(corr, topw, topi);
    agg_k<<<dim3(64, 128), 256, 0, stream>>>(Vstage, topw, topi, Y);
    gemm_o_k<<<dim3(256, 8), 256, 0, stream>>>(Y, Wof, bo, out);
}

// Round 17
// 1615.904 us; speedup vs baseline: 4.1497x; 4.1497x over previous
//
#include <hip/hip_runtime.h>

#define DEVI static __device__ __forceinline__

typedef float    f32x4 __attribute__((ext_vector_type(4)));
typedef _Float16 f16x8 __attribute__((ext_vector_type(8)));

static constexpr int Bn = 8, Ln = 4096, Dn = 1024, Hn = 16, DKn = 64;
static constexpr int TOPK = 8;
static constexpr float LO_SCALE = 2048.f, LO_INV = 1.f / 2048.f;

DEVI f32x4 mfma_f16(f16x8 a, f16x8 b, f32x4 c) {
    return __builtin_amdgcn_mfma_f32_16x16x32_f16(a, b, c, 0, 0, 0);
}

struct HL { _Float16 hi, lo; };
DEVI HL split2(float x) {
    HL r;
    r.hi = (_Float16)x;
    r.lo = (_Float16)((x - (float)r.hi) * LO_SCALE);
    return r;
}

DEVI void gload16(const void* g, void* l) {
    __builtin_amdgcn_global_load_lds(
        (const __attribute__((address_space(1))) unsigned int*)g,
        (__attribute__((address_space(3))) unsigned int*)l,
        16, 0, 0);
}

// ---------------------------------------------------------------------------
// conversion kernels (memory-bound)
// ---------------------------------------------------------------------------
__global__ __launch_bounds__(256) void cvt_split_k(
    const float* __restrict__ srcA, _Float16* __restrict__ hiA, _Float16* __restrict__ loA,
    const float* __restrict__ srcB, _Float16* __restrict__ hiB, _Float16* __restrict__ loB,
    int n8)
{
    const float* s  = blockIdx.y ? srcB : srcA;
    _Float16*    ph = blockIdx.y ? hiB  : hiA;
    _Float16*    pl = blockIdx.y ? loB  : loA;
    const int idx = blockIdx.x * 256 + threadIdx.x;
    if (idx >= n8) return;
    f32x4 x0 = *(const f32x4*)(s + (size_t)idx * 8);
    f32x4 x1 = *(const f32x4*)(s + (size_t)idx * 8 + 4);
    f16x8 h, l;
#pragma unroll
    for (int j = 0; j < 4; j++) {
        HL p0 = split2(x0[j]), p1 = split2(x1[j]);
        h[j] = p0.hi; l[j] = p0.lo;
        h[4 + j] = p1.hi; l[4 + j] = p1.lo;
    }
    *(f16x8*)(ph + (size_t)idx * 8) = h;
    *(f16x8*)(pl + (size_t)idx * 8) = l;
}

__global__ __launch_bounds__(256) void cvt_f16_k(
    const float* __restrict__ srcA, _Float16* __restrict__ dstA,
    const float* __restrict__ srcB, _Float16* __restrict__ dstB, int n8)
{
    const float* s = blockIdx.y ? srcB : srcA;
    _Float16*    d = blockIdx.y ? dstB : dstA;
    const int idx = blockIdx.x * 256 + threadIdx.x;
    if (idx >= n8) return;
    f32x4 x0 = *(const f32x4*)(s + (size_t)idx * 8);
    f32x4 x1 = *(const f32x4*)(s + (size_t)idx * 8 + 4);
    f16x8 o;
#pragma unroll
    for (int j = 0; j < 4; j++) { o[j] = (_Float16)x0[j]; o[4 + j] = (_Float16)x1[j]; }
    *(f16x8*)(d + (size_t)idx * 8) = o;
}

// ---------------------------------------------------------------------------
// m97-structure GEMM: C[m,n] = sum_k A[m,k]*W[n,k] + bias[n], K = 1024.
// 128x128 tile, BK=32, 4 waves, global_load_lds staging, 2-barrier K-loop.
// COMP: A and W in hi + scaled-lo f16 pairs; 3-term compensated MFMA.
// AF32: A staged raw f32 (swizzled source), cast at fragment load (gemm_v).
// MODE 0: out0 f32 row-major [M][1024]                  (final O-proj)
// MODE 1: out0 f16 head-split [b][h][l][64], b=m>>12    (V staging)
// MODE 2: out0 f32 TRANSPOSED [b2][n][l] via LDS-transpose epilogue,
//         coalesced 512B-row stores. Epilogue j-loop FULLY UNROLLED --
//         runtime-indexed acc[][] would demote accumulators to scratch
//         (rule #20; round-16 regression: VGPR 52, 7GB scratch traffic).
// ---------------------------------------------------------------------------
DEVI void stage8(const _Float16* gbase, _Float16* ltile, int w, int lane, int k0) {
#pragma unroll
    for (int c = 0; c < 2; c++) {
        const int chunk = 2 * w + c;
        const int row = chunk * 16 + (lane >> 2);
        gload16(gbase + (size_t)row * Dn + k0 + (lane & 3) * 8, ltile + chunk * 512);
    }
}

DEVI void stage16f32(const float* gbase, float* ltile, int w, int lane, int k0) {
    const int r    = lane >> 3;
    const int gsrc = (lane & 7) ^ r;
#pragma unroll
    for (int c = 0; c < 4; c++) {
        const int chunk = w * 4 + c;
        const int row = chunk * 8 + r;
        gload16(gbase + (size_t)row * Dn + k0 + gsrc * 4, ltile + chunk * 256);
    }
}

template<int MODE, bool COMP, bool AF32>
DEVI void gemm4_body(
    const void* __restrict__ A_hi, const _Float16* __restrict__ A_lo,
    const _Float16* __restrict__ W_hi, const _Float16* __restrict__ W_lo,
    const float* __restrict__ bias, void* __restrict__ out0)
{
    constexpr int ASZ = (AF32 || COMP) ? 16384 : 8192;
    __shared__ char smem[ASZ + (COMP ? 16384 : 8192)];
    float*    sAf = (float*)smem;
    _Float16* sAh = (_Float16*)smem;
    _Float16* sAl = (_Float16*)(smem + 8192);      // COMP only
    _Float16* sWh = (_Float16*)(smem + ASZ);
    _Float16* sWl = (_Float16*)(smem + ASZ + 8192);

    const int l  = threadIdx.x & 63;
    const int w  = threadIdx.x >> 6;
    const int m0 = blockIdx.x * 128;
    const int n0 = blockIdx.y * 128;
    const int wm = (w & 1) * 64, wn = (w >> 1) * 64;
    const int rr = l & 15, ko = (l >> 4) * 8, g0 = (l >> 4) * 2;

    const _Float16* Wbh = W_hi + (size_t)n0 * Dn;
    const _Float16* Wbl = COMP ? W_lo + (size_t)n0 * Dn : nullptr;

    f32x4 acc[4][4] = {};
    f32x4 accc[4][4] = {};

    for (int k0 = 0; k0 < Dn; k0 += 32) {
        if (AF32) {
            stage16f32((const float*)A_hi + (size_t)m0 * Dn, sAf, w, l, k0);
        } else {
            stage8((const _Float16*)A_hi + (size_t)m0 * Dn, sAh, w, l, k0);
            if (COMP) stage8(A_lo + (size_t)m0 * Dn, sAl, w, l, k0);
        }
        stage8(Wbh, sWh, w, l, k0);
        if (COMP) stage8(Wbl, sWl, w, l, k0);
        __syncthreads();

        f16x8 af[4], alf[4], bf[4], blf[4];
#pragma unroll
        for (int i = 0; i < 4; i++) {
            const int arow = wm + 16 * i + rr;
            if (AF32) {
                const float* rb = &sAf[arow * 32];
                f32x4 x0 = *(const f32x4*)&rb[((g0    ) ^ (arow & 7)) * 4];
                f32x4 x1 = *(const f32x4*)&rb[((g0 + 1) ^ (arow & 7)) * 4];
#pragma unroll
                for (int j = 0; j < 4; j++) {
                    af[i][j]     = (_Float16)x0[j];
                    af[i][4 + j] = (_Float16)x1[j];
                }
            } else {
                af[i] = *(const f16x8*)&sAh[arow * 32 + ko];
                if (COMP) alf[i] = *(const f16x8*)&sAl[arow * 32 + ko];
            }
            bf[i] = *(const f16x8*)&sWh[(wn + 16 * i + rr) * 32 + ko];
            if (COMP) blf[i] = *(const f16x8*)&sWl[(wn + 16 * i + rr) * 32 + ko];
        }
#pragma unroll
        for (int i = 0; i < 4; i++)
#pragma unroll
            for (int j = 0; j < 4; j++) {
                acc[i][j] = mfma_f16(af[i], bf[j], acc[i][j]);
                if (COMP) {
                    accc[i][j] = mfma_f16(alf[i], bf[j], accc[i][j]);
                    accc[i][j] = mfma_f16(af[i], blf[j], accc[i][j]);
                }
            }
        __syncthreads();
    }

    if (MODE == 2) {
        // LDS-transpose epilogue: coalesced stores to [b2][n][l] f32.
        float* sT = (float*)smem;          // 32 x 132 f32 (16.9KB, smem free)
        const int b2 = m0 >> 12;
        const int mb = m0 & (Ln - 1);
        const int npr = (wn >> 6) * 16 + rr;           // n' in [0,32)
#pragma unroll
        for (int j = 0; j < 4; j++) {      // FULLY UNROLLED (rule #20)
            __syncthreads();
            const float bs = bias[n0 + wn + 16 * j + rr];
#pragma unroll
            for (int i = 0; i < 4; i++)
#pragma unroll
                for (int r = 0; r < 4; r++) {
                    float v = acc[i][j][r] + accc[i][j][r] * LO_INV + bs;
                    sT[npr * 132 + wm + 16 * i + (l >> 4) * 4 + r] = v;
                }
            __syncthreads();
            const int row = threadIdx.x >> 3;          // [0,32)
            const int cb  = (threadIdx.x & 7) * 16;
            const int n   = n0 + (row >> 4) * 64 + 16 * j + (row & 15);
            float* dst = (float*)out0 + ((size_t)(b2 * 1024 + n)) * Ln + mb + cb;
            const float* sp = &sT[row * 132 + cb];
#pragma unroll
            for (int c4 = 0; c4 < 4; c4++)
                *(f32x4*)(dst + 4 * c4) = *(const f32x4*)(sp + 4 * c4);
        }
        return;
    }

#pragma unroll
    for (int i = 0; i < 4; i++)
#pragma unroll
        for (int j = 0; j < 4; j++)
#pragma unroll
            for (int r = 0; r < 4; r++) {
                const int m = m0 + wm + 16 * i + (l >> 4) * 4 + r;
                const int n = n0 + wn + 16 * j + (l & 15);
                float v = acc[i][j][r] + bias[n];
                if (MODE == 0) {
                    ((float*)out0)[(size_t)m * Dn + n] = v;
                } else {
                    size_t idx = ((size_t)((m >> 12) * Hn + (n >> 6)) * Ln
                                  + (m & (Ln - 1))) * DKn + (n & 63);
                    ((_Float16*)out0)[idx] = (_Float16)v;
                }
            }
}

__global__ __launch_bounds__(256) void gemm_v_k(
    const float* __restrict__ xv, const _Float16* __restrict__ Wv,
    const float* __restrict__ bv, _Float16* __restrict__ Vstage)
{
    gemm4_body<1, false, true>(xv, nullptr, Wv, nullptr, bv, Vstage);
}

__global__ __launch_bounds__(256) void gemm_o_k(
    const _Float16* __restrict__ Y, const _Float16* __restrict__ Wo,
    const float* __restrict__ bo, float* __restrict__ out)
{
    gemm4_body<0, false, false>(Y, nullptr, Wo, nullptr, bo, out);
}

// 2 batches per launch (M=8192); z=0 -> Q, z=1 -> K. Pre-split f16 inputs.
__global__ __launch_bounds__(256) void gemm_qk_k(
    const _Float16* __restrict__ xqhi, const _Float16* __restrict__ xqlo,
    const _Float16* __restrict__ xkhi, const _Float16* __restrict__ xklo,
    const _Float16* __restrict__ Wqhi, const _Float16* __restrict__ Wqlo,
    const _Float16* __restrict__ Wkhi, const _Float16* __restrict__ Wklo,
    const float* __restrict__ bq, const float* __restrict__ bk,
    float* __restrict__ QT, float* __restrict__ KT)
{
    if (blockIdx.z == 0)
        gemm4_body<2, true, false>(xqhi, xqlo, Wqhi, Wqlo, bq, QT);
    else
        gemm4_body<2, true, false>(xkhi, xklo, Wkhi, Wklo, bk, KT);
}

// ---------------------------------------------------------------------------
// FFT-based correlation (unchanged, verified).
// ---------------------------------------------------------------------------
DEVI int FPAD(int i) { return i + (i >> 4); }

DEVI float2 cmulf(float2 a, float2 b) {
    return make_float2(a.x * b.x - a.y * b.y, a.x * b.y + a.y * b.x);
}

DEVI void fft_pass(const float2* in, float2* out, int ls2, int tid) {
    const int Ns = 1 << ls2;
#pragma unroll
    for (int r = 0; r < 4; r++) {
        const int j = tid + r * 256;
        float2 v0 = in[FPAD(j)];
        float2 v1 = in[FPAD(j + 1024)];
        float2 v2 = in[FPAD(j + 2048)];
        float2 v3 = in[FPAD(j + 3072)];
        const int p = j & (Ns - 1);
        const float ang = -6.283185307179586f * (float)p / (4.f * (float)Ns);
        float sn, cs;
        __sincosf(ang, &sn, &cs);
        const float2 w1 = make_float2(cs, sn);
        const float2 w2 = cmulf(w1, w1);
        const float2 w3 = cmulf(w2, w1);
        v1 = cmulf(v1, w1); v2 = cmulf(v2, w2); v3 = cmulf(v3, w3);
        const float2 t0 = make_float2(v0.x + v2.x, v0.y + v2.y);
        const float2 t1 = make_float2(v0.x - v2.x, v0.y - v2.y);
        const float2 t2 = make_float2(v1.x + v3.x, v1.y + v3.y);
        const float2 t3 = make_float2(v1.x - v3.x, v1.y - v3.y);
        const float2 t3i = make_float2(t3.y, -t3.x);
        const int db = ((j >> ls2) << (ls2 + 2)) | p;
        out[FPAD(db)]          = make_float2(t0.x + t2.x, t0.y + t2.y);
        out[FPAD(db + Ns)]     = make_float2(t1.x + t3i.x, t1.y + t3i.y);
        out[FPAD(db + 2 * Ns)] = make_float2(t0.x - t2.x, t0.y - t2.y);
        out[FPAD(db + 3 * Ns)] = make_float2(t1.x - t3i.x, t1.y - t3i.y);
    }
}

DEVI void fft4096(float2* A, float2* B, int tid) {
    __syncthreads();
    fft_pass(A, B, 0, tid);  __syncthreads();
    fft_pass(B, A, 2, tid);  __syncthreads();
    fft_pass(A, B, 4, tid);  __syncthreads();
    fft_pass(B, A, 6, tid);  __syncthreads();
    fft_pass(A, B, 8, tid);  __syncthreads();
    fft_pass(B, A, 10, tid); __syncthreads();
}

__global__ __launch_bounds__(256) void fftcorr_k(
    const float* __restrict__ QT, const float* __restrict__ KT,
    float2* __restrict__ Pf)
{
    __shared__ float2 A[4352], B[4352];
    const int tid = threadIdx.x;
    const int bh  = blockIdx.y;
    const int d0  = blockIdx.x * 4;
    float2 acc[16];
#pragma unroll
    for (int i = 0; i < 16; i++) acc[i] = make_float2(0.f, 0.f);
    float2 qf[16];

    for (int dd = 0; dd < 4; dd++) {
        const int d = d0 + dd;
        const float* qc = QT + ((size_t)bh * 64 + d) * Ln;
        const float* kc = KT + ((size_t)bh * 64 + d) * Ln;
#pragma unroll
        for (int i = 0; i < 16; i++) {
            const int row = tid + 256 * i;
            A[FPAD(row)] = make_float2(qc[row], 0.f);
        }
        fft4096(A, B, tid);
#pragma unroll
        for (int i = 0; i < 16; i++) qf[i] = A[FPAD(tid + 256 * i)];
        __syncthreads();
#pragma unroll
        for (int i = 0; i < 16; i++) {
            const int row = tid + 256 * i;
            A[FPAD(row)] = make_float2(kc[row], 0.f);
        }
        fft4096(A, B, tid);
#pragma unroll
        for (int i = 0; i < 16; i++) {
            float2 kf = A[FPAD(tid + 256 * i)];
            acc[i].x += qf[i].x * kf.x + qf[i].y * kf.y;
            acc[i].y += qf[i].y * kf.x - qf[i].x * kf.y;
        }
        __syncthreads();
    }
    float2* P = Pf + (size_t)bh * Ln;
#pragma unroll
    for (int i = 0; i < 16; i++) {
        atomicAdd(&P[tid + 256 * i].x, acc[i].x);
        atomicAdd(&P[tid + 256 * i].y, acc[i].y);
    }
}

__global__ __launch_bounds__(256) void ifftcorr_k(
    const float2* __restrict__ Pf, float* __restrict__ corr)
{
    __shared__ float2 A[4352], B[4352];
    const int tid = threadIdx.x;
    const int bh = blockIdx.x;
    const float2* P = Pf + (size_t)bh * Ln;
#pragma unroll
    for (int i = 0; i < 16; i++) {
        float2 v = P[tid + 256 * i];
        A[FPAD(tid + 256 * i)] = make_float2(v.x, -v.y);
    }
    fft4096(A, B, tid);
#pragma unroll
    for (int i = 0; i < 16; i++)
        corr[(size_t)bh * Ln + tid + 256 * i] =
            A[FPAD(tid + 256 * i)].x * (1.f / 4096.f);
}

// ---------------------------------------------------------------------------
// Top-8 + softmax per (b,h) row of corr (raw sums; /64 before softmax).
// ---------------------------------------------------------------------------
__global__ __launch_bounds__(256) void topk_k(
    const float* __restrict__ corr, float* __restrict__ top_w,
    int* __restrict__ top_idx)
{
    __shared__ float vals[Ln];
    __shared__ float rv[256];
    __shared__ int   ri[256];
    __shared__ float sel_v[TOPK];
    __shared__ int   sel_i[TOPK];
    const int bh = blockIdx.x;
    const float* c = corr + (size_t)bh * Ln;
    for (int i = threadIdx.x; i < Ln; i += 256) vals[i] = c[i];
    __syncthreads();

    for (int it = 0; it < TOPK; it++) {
        float bvv = -1e30f; int bi = 0;
        const int base = threadIdx.x * 16;
#pragma unroll
        for (int j = 0; j < 16; j++) {
            float v = vals[base + j];
            if (v > bvv) { bvv = v; bi = base + j; }
        }
        rv[threadIdx.x] = bvv; ri[threadIdx.x] = bi;
        __syncthreads();
        if (threadIdx.x == 0) {
            float gv = rv[0]; int gi = ri[0];
            for (int t = 1; t < 256; t++)
                if (rv[t] > gv) { gv = rv[t]; gi = ri[t]; }
            sel_v[it] = gv; sel_i[it] = gi;
            vals[gi] = -1e30f;
        }
        __syncthreads();
    }
    if (threadIdx.x == 0) {
        float e[TOPK], s = 0.f;
        for (int i = 0; i < TOPK; i++) {
            e[i] = expf((sel_v[i] - sel_v[0]) * (1.f / 64.f));
            s += e[i];
        }
        for (int i = 0; i < TOPK; i++) {
            top_w[bh * TOPK + i]   = e[i] / s;
            top_idx[bh * TOPK + i] = sel_i[i];
        }
    }
}

// ---------------------------------------------------------------------------
// Aggregation: Y[b][t][h*64+d] = sum_i w_i * V[b][h][(t-idx_i)&4095][d]
// ---------------------------------------------------------------------------
__global__ __launch_bounds__(256) void agg_k(
    const _Float16* __restrict__ V /* [B][H][L][64] */,
    const float* __restrict__ top_w, const int* __restrict__ top_idx,
    _Float16* __restrict__ Y /* [B][L][1024] */)
{
    __shared__ float w_s[TOPK];
    __shared__ int   i_s[TOPK];
    const int bh   = blockIdx.y;
    const int b    = bh >> 4, h = bh & 15;
    const int tloc = threadIdx.x >> 2;
    const int c16  = (threadIdx.x & 3) * 16;
    const int t    = blockIdx.x * 64 + tloc;
    if (threadIdx.x < TOPK) {
        w_s[threadIdx.x] = top_w[bh * TOPK + threadIdx.x];
        i_s[threadIdx.x] = top_idx[bh * TOPK + threadIdx.x];
    }
    __syncthreads();

    const _Float16* Vb = V + (size_t)bh * Ln * DKn;
    float acc[16] = {};
#pragma unroll
    for (int i = 0; i < TOPK; i++) {
        const int src = (t - i_s[i]) & (Ln - 1);
        const _Float16* p = Vb + (size_t)src * DKn + c16;
        f16x8 v0 = *(const f16x8*)(p);
        f16x8 v1 = *(const f16x8*)(p + 8);
        const float wgt = w_s[i];
#pragma unroll
        for (int j = 0; j < 8; j++) acc[j]     += wgt * (float)v0[j];
#pragma unroll
        for (int j = 0; j < 8; j++) acc[8 + j] += wgt * (float)v1[j];
    }
    f16x8 o0, o1;
#pragma unroll
    for (int j = 0; j < 8; j++) { o0[j] = (_Float16)acc[j]; o1[j] = (_Float16)acc[8 + j]; }
    const size_t oidx = ((size_t)(b * Ln + t)) * Dn + h * DKn + c16;
    *(f16x8*)(Y + oidx)     = o0;
    *(f16x8*)(Y + oidx + 8) = o1;
}

// ---------------------------------------------------------------------------
extern "C" void kernel_launch(void* const* d_in, const int* in_sizes, int n_in,
                              void* d_out, int out_size, void* d_ws, size_t ws_size,
                              hipStream_t stream)
{
    const float* q  = (const float*)d_in[0];
    const float* kk = (const float*)d_in[1];
    const float* v  = (const float*)d_in[2];
    const float* Wq = (const float*)d_in[3];
    const float* bq = (const float*)d_in[4];
    const float* Wk = (const float*)d_in[5];
    const float* bk = (const float*)d_in[6];
    const float* Wv = (const float*)d_in[7];
    const float* bv = (const float*)d_in[8];
    const float* Wo = (const float*)d_in[9];
    const float* bo = (const float*)d_in[10];
    float* out = (float*)d_out;

    // ws layout (bytes):
    //   QT f32 [2][1024][4096] @0 ; KT @33554432 ; Y overlays @0 after loop
    //   corr @67108864 ; topw @69206016 ; topi @69210112
    //   Wqhi @69214208 ; Wqlo @71311360 ; Wkhi @73408512 ; Wklo @75505664
    //   Wvf @77602816 ; Wof @79699968 ; Pf cf32[128][4096] @81797120
    char* ws = (char*)d_ws;
    if (ws_size < 85991424ull) return;
    float*    QT   = (float*)(ws);
    float*    KT   = (float*)(ws + 33554432);
    _Float16* Y    = (_Float16*)(ws);
    float*    corr = (float*)(ws + 67108864);
    float*    topw = (float*)(ws + 69206016);
    int*      topi = (int*)(ws + 69210112);
    _Float16* Wqhi = (_Float16*)(ws + 69214208);
    _Float16* Wqlo = (_Float16*)(ws + 71311360);
    _Float16* Wkhi = (_Float16*)(ws + 73408512);
    _Float16* Wklo = (_Float16*)(ws + 75505664);
    _Float16* Wvf  = (_Float16*)(ws + 77602816);
    _Float16* Wof  = (_Float16*)(ws + 79699968);
    float2*   Pf   = (float2*)(ws + 81797120);

    // d_out (128MiB): Vstage f16 [8][16][4096][64] @0 (64MiB);
    // upper 64MiB = per-pair x-split scratch (4 x 16MiB f16 [2][4096][1024]).
    _Float16* Vstage = (_Float16*)d_out;
    _Float16* xqhi = (_Float16*)((char*)d_out + 67108864);
    _Float16* xqlo = (_Float16*)((char*)d_out + 83886080);
    _Float16* xkhi = (_Float16*)((char*)d_out + 100663296);
    _Float16* xklo = (_Float16*)((char*)d_out + 117440512);

    (void)hipMemsetAsync(Pf, 0, (size_t)128 * Ln * sizeof(float2), stream);

    cvt_split_k<<<dim3(512, 2), 256, 0, stream>>>(Wq, Wqhi, Wqlo, Wk, Wkhi, Wklo, 131072);
    cvt_f16_k<<<dim3(512, 2), 256, 0, stream>>>(Wv, Wvf, Wo, Wof, 131072);

    gemm_v_k<<<dim3(256, 8), 256, 0, stream>>>(v, Wvf, bv, Vstage);

    for (int p = 0; p < 4; p++) {
        cvt_split_k<<<dim3(4096, 2), 256, 0, stream>>>(
            q + (size_t)p * 2 * Ln * Dn, xqhi, xqlo,
            kk + (size_t)p * 2 * Ln * Dn, xkhi, xklo, 1048576);
        gemm_qk_k<<<dim3(64, 8, 2), 256, 0, stream>>>(
            xqhi, xqlo, xkhi, xklo,
            Wqhi, Wqlo, Wkhi, Wklo, bq, bk, QT, KT);
        fftcorr_k<<<dim3(16, 32), 256, 0, stream>>>(QT, KT, Pf + (size_t)p * 32 * Ln);
    }
    ifftcorr_k<<<128, 256, 0, stream>>>(Pf, corr);
    topk_k<<<128, 256, 0, stream>>>(corr, topw, topi);
    agg_k<<<dim3(64, 128), 256, 0, stream>>>(Vstage, topw, topi, Y);
    gemm_o_k<<<dim3(256, 8), 256, 0, stream>>>(Y, Wof, bo, out);
}

// Round 18
// 1415.552 us; speedup vs baseline: 4.7371x; 1.1415x over previous
//
#include <hip/hip_runtime.h>

#define DEVI static __device__ __forceinline__

typedef float    f32x4 __attribute__((ext_vector_type(4)));
typedef _Float16 f16x8 __attribute__((ext_vector_type(8)));

static constexpr int Bn = 8, Ln = 4096, Dn = 1024, Hn = 16, DKn = 64;
static constexpr int TOPK = 8;
static constexpr float LO_SCALE = 2048.f, LO_INV = 1.f / 2048.f;

DEVI f32x4 mfma_f16(f16x8 a, f16x8 b, f32x4 c) {
    return __builtin_amdgcn_mfma_f32_16x16x32_f16(a, b, c, 0, 0, 0);
}

struct HL { _Float16 hi, lo; };
DEVI HL split2(float x) {
    HL r;
    r.hi = (_Float16)x;
    r.lo = (_Float16)((x - (float)r.hi) * LO_SCALE);
    return r;
}

DEVI void gload16(const void* g, void* l) {
    __builtin_amdgcn_global_load_lds(
        (const __attribute__((address_space(1))) unsigned int*)g,
        (__attribute__((address_space(3))) unsigned int*)l,
        16, 0, 0);
}

// ---------------------------------------------------------------------------
// conversion kernels (memory-bound)
// ---------------------------------------------------------------------------
__global__ __launch_bounds__(256) void cvt_split_k(
    const float* __restrict__ srcA, _Float16* __restrict__ hiA, _Float16* __restrict__ loA,
    const float* __restrict__ srcB, _Float16* __restrict__ hiB, _Float16* __restrict__ loB,
    int n8)
{
    const float* s  = blockIdx.y ? srcB : srcA;
    _Float16*    ph = blockIdx.y ? hiB  : hiA;
    _Float16*    pl = blockIdx.y ? loB  : loA;
    const int idx = blockIdx.x * 256 + threadIdx.x;
    if (idx >= n8) return;
    f32x4 x0 = *(const f32x4*)(s + (size_t)idx * 8);
    f32x4 x1 = *(const f32x4*)(s + (size_t)idx * 8 + 4);
    f16x8 h, l;
#pragma unroll
    for (int j = 0; j < 4; j++) {
        HL p0 = split2(x0[j]), p1 = split2(x1[j]);
        h[j] = p0.hi; l[j] = p0.lo;
        h[4 + j] = p1.hi; l[4 + j] = p1.lo;
    }
    *(f16x8*)(ph + (size_t)idx * 8) = h;
    *(f16x8*)(pl + (size_t)idx * 8) = l;
}

__global__ __launch_bounds__(256) void cvt_f16_k(
    const float* __restrict__ srcA, _Float16* __restrict__ dstA,
    const float* __restrict__ srcB, _Float16* __restrict__ dstB, int n8)
{
    const float* s = blockIdx.y ? srcB : srcA;
    _Float16*    d = blockIdx.y ? dstB : dstA;
    const int idx = blockIdx.x * 256 + threadIdx.x;
    if (idx >= n8) return;
    f32x4 x0 = *(const f32x4*)(s + (size_t)idx * 8);
    f32x4 x1 = *(const f32x4*)(s + (size_t)idx * 8 + 4);
    f16x8 o;
#pragma unroll
    for (int j = 0; j < 4; j++) { o[j] = (_Float16)x0[j]; o[4 + j] = (_Float16)x1[j]; }
    *(f16x8*)(d + (size_t)idx * 8) = o;
}

// ---------------------------------------------------------------------------
// m97-structure GEMM (unchanged from round 17, verified).
// ---------------------------------------------------------------------------
DEVI void stage8(const _Float16* gbase, _Float16* ltile, int w, int lane, int k0) {
#pragma unroll
    for (int c = 0; c < 2; c++) {
        const int chunk = 2 * w + c;
        const int row = chunk * 16 + (lane >> 2);
        gload16(gbase + (size_t)row * Dn + k0 + (lane & 3) * 8, ltile + chunk * 512);
    }
}

DEVI void stage16f32(const float* gbase, float* ltile, int w, int lane, int k0) {
    const int r    = lane >> 3;
    const int gsrc = (lane & 7) ^ r;
#pragma unroll
    for (int c = 0; c < 4; c++) {
        const int chunk = w * 4 + c;
        const int row = chunk * 8 + r;
        gload16(gbase + (size_t)row * Dn + k0 + gsrc * 4, ltile + chunk * 256);
    }
}

template<int MODE, bool COMP, bool AF32>
DEVI void gemm4_body(
    const void* __restrict__ A_hi, const _Float16* __restrict__ A_lo,
    const _Float16* __restrict__ W_hi, const _Float16* __restrict__ W_lo,
    const float* __restrict__ bias, void* __restrict__ out0)
{
    constexpr int ASZ = (AF32 || COMP) ? 16384 : 8192;
    __shared__ char smem[ASZ + (COMP ? 16384 : 8192)];
    float*    sAf = (float*)smem;
    _Float16* sAh = (_Float16*)smem;
    _Float16* sAl = (_Float16*)(smem + 8192);      // COMP only
    _Float16* sWh = (_Float16*)(smem + ASZ);
    _Float16* sWl = (_Float16*)(smem + ASZ + 8192);

    const int l  = threadIdx.x & 63;
    const int w  = threadIdx.x >> 6;
    const int m0 = blockIdx.x * 128;
    const int n0 = blockIdx.y * 128;
    const int wm = (w & 1) * 64, wn = (w >> 1) * 64;
    const int rr = l & 15, ko = (l >> 4) * 8, g0 = (l >> 4) * 2;

    const _Float16* Wbh = W_hi + (size_t)n0 * Dn;
    const _Float16* Wbl = COMP ? W_lo + (size_t)n0 * Dn : nullptr;

    f32x4 acc[4][4] = {};
    f32x4 accc[4][4] = {};

    for (int k0 = 0; k0 < Dn; k0 += 32) {
        if (AF32) {
            stage16f32((const float*)A_hi + (size_t)m0 * Dn, sAf, w, l, k0);
        } else {
            stage8((const _Float16*)A_hi + (size_t)m0 * Dn, sAh, w, l, k0);
            if (COMP) stage8(A_lo + (size_t)m0 * Dn, sAl, w, l, k0);
        }
        stage8(Wbh, sWh, w, l, k0);
        if (COMP) stage8(Wbl, sWl, w, l, k0);
        __syncthreads();

        f16x8 af[4], alf[4], bf[4], blf[4];
#pragma unroll
        for (int i = 0; i < 4; i++) {
            const int arow = wm + 16 * i + rr;
            if (AF32) {
                const float* rb = &sAf[arow * 32];
                f32x4 x0 = *(const f32x4*)&rb[((g0    ) ^ (arow & 7)) * 4];
                f32x4 x1 = *(const f32x4*)&rb[((g0 + 1) ^ (arow & 7)) * 4];
#pragma unroll
                for (int j = 0; j < 4; j++) {
                    af[i][j]     = (_Float16)x0[j];
                    af[i][4 + j] = (_Float16)x1[j];
                }
            } else {
                af[i] = *(const f16x8*)&sAh[arow * 32 + ko];
                if (COMP) alf[i] = *(const f16x8*)&sAl[arow * 32 + ko];
            }
            bf[i] = *(const f16x8*)&sWh[(wn + 16 * i + rr) * 32 + ko];
            if (COMP) blf[i] = *(const f16x8*)&sWl[(wn + 16 * i + rr) * 32 + ko];
        }
#pragma unroll
        for (int i = 0; i < 4; i++)
#pragma unroll
            for (int j = 0; j < 4; j++) {
                acc[i][j] = mfma_f16(af[i], bf[j], acc[i][j]);
                if (COMP) {
                    accc[i][j] = mfma_f16(alf[i], bf[j], accc[i][j]);
                    accc[i][j] = mfma_f16(af[i], blf[j], accc[i][j]);
                }
            }
        __syncthreads();
    }

    if (MODE == 2) {
        // LDS-transpose epilogue: coalesced stores to [b2][n][l] f32.
        float* sT = (float*)smem;          // 32 x 132 f32
        const int b2 = m0 >> 12;
        const int mb = m0 & (Ln - 1);
        const int npr = (wn >> 6) * 16 + rr;
#pragma unroll
        for (int j = 0; j < 4; j++) {      // FULLY UNROLLED (rule #20)
            __syncthreads();
            const float bs = bias[n0 + wn + 16 * j + rr];
#pragma unroll
            for (int i = 0; i < 4; i++)
#pragma unroll
                for (int r = 0; r < 4; r++) {
                    float v = acc[i][j][r] + accc[i][j][r] * LO_INV + bs;
                    sT[npr * 132 + wm + 16 * i + (l >> 4) * 4 + r] = v;
                }
            __syncthreads();
            const int row = threadIdx.x >> 3;
            const int cb  = (threadIdx.x & 7) * 16;
            const int n   = n0 + (row >> 4) * 64 + 16 * j + (row & 15);
            float* dst = (float*)out0 + ((size_t)(b2 * 1024 + n)) * Ln + mb + cb;
            const float* sp = &sT[row * 132 + cb];
#pragma unroll
            for (int c4 = 0; c4 < 4; c4++)
                *(f32x4*)(dst + 4 * c4) = *(const f32x4*)(sp + 4 * c4);
        }
        return;
    }

#pragma unroll
    for (int i = 0; i < 4; i++)
#pragma unroll
        for (int j = 0; j < 4; j++)
#pragma unroll
            for (int r = 0; r < 4; r++) {
                const int m = m0 + wm + 16 * i + (l >> 4) * 4 + r;
                const int n = n0 + wn + 16 * j + (l & 15);
                float v = acc[i][j][r] + bias[n];
                if (MODE == 0) {
                    ((float*)out0)[(size_t)m * Dn + n] = v;
                } else {
                    size_t idx = ((size_t)((m >> 12) * Hn + (n >> 6)) * Ln
                                  + (m & (Ln - 1))) * DKn + (n & 63);
                    ((_Float16*)out0)[idx] = (_Float16)v;
                }
            }
}

__global__ __launch_bounds__(256) void gemm_v_k(
    const float* __restrict__ xv, const _Float16* __restrict__ Wv,
    const float* __restrict__ bv, _Float16* __restrict__ Vstage)
{
    gemm4_body<1, false, true>(xv, nullptr, Wv, nullptr, bv, Vstage);
}

__global__ __launch_bounds__(256) void gemm_o_k(
    const _Float16* __restrict__ Y, const _Float16* __restrict__ Wo,
    const float* __restrict__ bo, float* __restrict__ out)
{
    gemm4_body<0, false, false>(Y, nullptr, Wo, nullptr, bo, out);
}

__global__ __launch_bounds__(256) void gemm_qk_k(
    const _Float16* __restrict__ xqhi, const _Float16* __restrict__ xqlo,
    const _Float16* __restrict__ xkhi, const _Float16* __restrict__ xklo,
    const _Float16* __restrict__ Wqhi, const _Float16* __restrict__ Wqlo,
    const _Float16* __restrict__ Wkhi, const _Float16* __restrict__ Wklo,
    const float* __restrict__ bq, const float* __restrict__ bk,
    float* __restrict__ QT, float* __restrict__ KT)
{
    if (blockIdx.z == 0)
        gemm4_body<2, true, false>(xqhi, xqlo, Wqhi, Wqlo, bq, QT);
    else
        gemm4_body<2, true, false>(xkhi, xklo, Wkhi, Wklo, bk, KT);
}

// ---------------------------------------------------------------------------
// FFT-based correlation, v2:
//  - two-reals-in-one-complex pack: FFT(q + i*k) once; Qf/Kf recovered by
//    conjugate symmetry at product time (halves FFT passes: 24 -> 12/block).
//  - pad i + (i>>4) + (i>>8): radix-4 taps (1024/2048/3072) land on bank
//    offsets 8/16/24 instead of all 0 (the old pad made them collide).
// ---------------------------------------------------------------------------
DEVI int FPAD(int i) { return i + (i >> 4) + (i >> 8); }

DEVI float2 cmulf(float2 a, float2 b) {
    return make_float2(a.x * b.x - a.y * b.y, a.x * b.y + a.y * b.x);
}

DEVI void fft_pass(const float2* in, float2* out, int ls2, int tid) {
    const int Ns = 1 << ls2;
#pragma unroll
    for (int r = 0; r < 4; r++) {
        const int j = tid + r * 256;
        float2 v0 = in[FPAD(j)];
        float2 v1 = in[FPAD(j + 1024)];
        float2 v2 = in[FPAD(j + 2048)];
        float2 v3 = in[FPAD(j + 3072)];
        const int p = j & (Ns - 1);
        const float ang = -6.283185307179586f * (float)p / (4.f * (float)Ns);
        float sn, cs;
        __sincosf(ang, &sn, &cs);
        const float2 w1 = make_float2(cs, sn);
        const float2 w2 = cmulf(w1, w1);
        const float2 w3 = cmulf(w2, w1);
        v1 = cmulf(v1, w1); v2 = cmulf(v2, w2); v3 = cmulf(v3, w3);
        const float2 t0 = make_float2(v0.x + v2.x, v0.y + v2.y);
        const float2 t1 = make_float2(v0.x - v2.x, v0.y - v2.y);
        const float2 t2 = make_float2(v1.x + v3.x, v1.y + v3.y);
        const float2 t3 = make_float2(v1.x - v3.x, v1.y - v3.y);
        const float2 t3i = make_float2(t3.y, -t3.x);
        const int db = ((j >> ls2) << (ls2 + 2)) | p;
        out[FPAD(db)]          = make_float2(t0.x + t2.x, t0.y + t2.y);
        out[FPAD(db + Ns)]     = make_float2(t1.x + t3i.x, t1.y + t3i.y);
        out[FPAD(db + 2 * Ns)] = make_float2(t0.x - t2.x, t0.y - t2.y);
        out[FPAD(db + 3 * Ns)] = make_float2(t1.x - t3i.x, t1.y - t3i.y);
    }
}

DEVI void fft4096(float2* A, float2* B, int tid) {
    __syncthreads();
    fft_pass(A, B, 0, tid);  __syncthreads();
    fft_pass(B, A, 2, tid);  __syncthreads();
    fft_pass(A, B, 4, tid);  __syncthreads();
    fft_pass(B, A, 6, tid);  __syncthreads();
    fft_pass(A, B, 8, tid);  __syncthreads();
    fft_pass(B, A, 10, tid); __syncthreads();
}

__global__ __launch_bounds__(256) void fftcorr_k(
    const float* __restrict__ QT, const float* __restrict__ KT,
    float2* __restrict__ Pf)
{
    __shared__ float2 A[4368], B[4368];
    const int tid = threadIdx.x;
    const int bh  = blockIdx.y;
    const int d0  = blockIdx.x * 4;
    float2 acc[16];
#pragma unroll
    for (int i = 0; i < 16; i++) acc[i] = make_float2(0.f, 0.f);

    for (int dd = 0; dd < 4; dd++) {
        const int d = d0 + dd;
        const float* qc = QT + ((size_t)bh * 64 + d) * Ln;
        const float* kc = KT + ((size_t)bh * 64 + d) * Ln;
#pragma unroll
        for (int i = 0; i < 16; i++) {
            const int row = tid + 256 * i;
            A[FPAD(row)] = make_float2(qc[row], kc[row]);   // z = q + i*k
        }
        fft4096(A, B, tid);
        // Qf[t] = (Z[t]+conj(Z[-t]))/2 ; Kf[t] = -i(Z[t]-conj(Z[-t]))/2
        // acc += Qf * conj(Kf)
#pragma unroll
        for (int i = 0; i < 16; i++) {
            const int t  = tid + 256 * i;
            const int tm = (Ln - t) & (Ln - 1);
            float2 Zt = A[FPAD(t)];
            float2 Zm = A[FPAD(tm)];
            const float qr = 0.5f * (Zt.x + Zm.x);
            const float qi = 0.5f * (Zt.y - Zm.y);
            const float kr = 0.5f * (Zt.y + Zm.y);
            const float ki = 0.5f * (Zm.x - Zt.x);
            acc[i].x += qr * kr + qi * ki;
            acc[i].y += qi * kr - qr * ki;
        }
        __syncthreads();
    }
    float2* P = Pf + (size_t)bh * Ln;
#pragma unroll
    for (int i = 0; i < 16; i++) {
        atomicAdd(&P[tid + 256 * i].x, acc[i].x);
        atomicAdd(&P[tid + 256 * i].y, acc[i].y);
    }
}

__global__ __launch_bounds__(256) void ifftcorr_k(
    const float2* __restrict__ Pf, float* __restrict__ corr)
{
    __shared__ float2 A[4368], B[4368];
    const int tid = threadIdx.x;
    const int bh = blockIdx.x;
    const float2* P = Pf + (size_t)bh * Ln;
#pragma unroll
    for (int i = 0; i < 16; i++) {
        float2 v = P[tid + 256 * i];
        A[FPAD(tid + 256 * i)] = make_float2(v.x, -v.y);
    }
    fft4096(A, B, tid);
#pragma unroll
    for (int i = 0; i < 16; i++)
        corr[(size_t)bh * Ln + tid + 256 * i] =
            A[FPAD(tid + 256 * i)].x * (1.f / 4096.f);
}

// ---------------------------------------------------------------------------
// Top-8 + softmax per (b,h) row of corr (raw sums; /64 before softmax).
// ---------------------------------------------------------------------------
__global__ __launch_bounds__(256) void topk_k(
    const float* __restrict__ corr, float* __restrict__ top_w,
    int* __restrict__ top_idx)
{
    __shared__ float vals[Ln];
    __shared__ float rv[256];
    __shared__ int   ri[256];
    __shared__ float sel_v[TOPK];
    __shared__ int   sel_i[TOPK];
    const int bh = blockIdx.x;
    const float* c = corr + (size_t)bh * Ln;
    for (int i = threadIdx.x; i < Ln; i += 256) vals[i] = c[i];
    __syncthreads();

    for (int it = 0; it < TOPK; it++) {
        float bvv = -1e30f; int bi = 0;
        const int base = threadIdx.x * 16;
#pragma unroll
        for (int j = 0; j < 16; j++) {
            float v = vals[base + j];
            if (v > bvv) { bvv = v; bi = base + j; }
        }
        rv[threadIdx.x] = bvv; ri[threadIdx.x] = bi;
        __syncthreads();
        if (threadIdx.x == 0) {
            float gv = rv[0]; int gi = ri[0];
            for (int t = 1; t < 256; t++)
                if (rv[t] > gv) { gv = rv[t]; gi = ri[t]; }
            sel_v[it] = gv; sel_i[it] = gi;
            vals[gi] = -1e30f;
        }
        __syncthreads();
    }
    if (threadIdx.x == 0) {
        float e[TOPK], s = 0.f;
        for (int i = 0; i < TOPK; i++) {
            e[i] = expf((sel_v[i] - sel_v[0]) * (1.f / 64.f));
            s += e[i];
        }
        for (int i = 0; i < TOPK; i++) {
            top_w[bh * TOPK + i]   = e[i] / s;
            top_idx[bh * TOPK + i] = sel_i[i];
        }
    }
}

// ---------------------------------------------------------------------------
// Aggregation: Y[b][t][h*64+d] = sum_i w_i * V[b][h][(t-idx_i)&4095][d]
// ---------------------------------------------------------------------------
__global__ __launch_bounds__(256) void agg_k(
    const _Float16* __restrict__ V /* [B][H][L][64] */,
    const float* __restrict__ top_w, const int* __restrict__ top_idx,
    _Float16* __restrict__ Y /* [B][L][1024] */)
{
    __shared__ float w_s[TOPK];
    __shared__ int   i_s[TOPK];
    const int bh   = blockIdx.y;
    const int b    = bh >> 4, h = bh & 15;
    const int tloc = threadIdx.x >> 2;
    const int c16  = (threadIdx.x & 3) * 16;
    const int t    = blockIdx.x * 64 + tloc;
    if (threadIdx.x < TOPK) {
        w_s[threadIdx.x] = top_w[bh * TOPK + threadIdx.x];
        i_s[threadIdx.x] = top_idx[bh * TOPK + threadIdx.x];
    }
    __syncthreads();

    const _Float16* Vb = V + (size_t)bh * Ln * DKn;
    float acc[16] = {};
#pragma unroll
    for (int i = 0; i < TOPK; i++) {
        const int src = (t - i_s[i]) & (Ln - 1);
        const _Float16* p = Vb + (size_t)src * DKn + c16;
        f16x8 v0 = *(const f16x8*)(p);
        f16x8 v1 = *(const f16x8*)(p + 8);
        const float wgt = w_s[i];
#pragma unroll
        for (int j = 0; j < 8; j++) acc[j]     += wgt * (float)v0[j];
#pragma unroll
        for (int j = 0; j < 8; j++) acc[8 + j] += wgt * (float)v1[j];
    }
    f16x8 o0, o1;
#pragma unroll
    for (int j = 0; j < 8; j++) { o0[j] = (_Float16)acc[j]; o1[j] = (_Float16)acc[8 + j]; }
    const size_t oidx = ((size_t)(b * Ln + t)) * Dn + h * DKn + c16;
    *(f16x8*)(Y + oidx)     = o0;
    *(f16x8*)(Y + oidx + 8) = o1;
}

// ---------------------------------------------------------------------------
extern "C" void kernel_launch(void* const* d_in, const int* in_sizes, int n_in,
                              void* d_out, int out_size, void* d_ws, size_t ws_size,
                              hipStream_t stream)
{
    const float* q  = (const float*)d_in[0];
    const float* kk = (const float*)d_in[1];
    const float* v  = (const float*)d_in[2];
    const float* Wq = (const float*)d_in[3];
    const float* bq = (const float*)d_in[4];
    const float* Wk = (const float*)d_in[5];
    const float* bk = (const float*)d_in[6];
    const float* Wv = (const float*)d_in[7];
    const float* bv = (const float*)d_in[8];
    const float* Wo = (const float*)d_in[9];
    const float* bo = (const float*)d_in[10];
    float* out = (float*)d_out;

    char* ws = (char*)d_ws;
    if (ws_size < 85991424ull) return;
    float*    QT   = (float*)(ws);
    float*    KT   = (float*)(ws + 33554432);
    _Float16* Y    = (_Float16*)(ws);
    float*    corr = (float*)(ws + 67108864);
    float*    topw = (float*)(ws + 69206016);
    int*      topi = (int*)(ws + 69210112);
    _Float16* Wqhi = (_Float16*)(ws + 69214208);
    _Float16* Wqlo = (_Float16*)(ws + 71311360);
    _Float16* Wkhi = (_Float16*)(ws + 73408512);
    _Float16* Wklo = (_Float16*)(ws + 75505664);
    _Float16* Wvf  = (_Float16*)(ws + 77602816);
    _Float16* Wof  = (_Float16*)(ws + 79699968);
    float2*   Pf   = (float2*)(ws + 81797120);

    _Float16* Vstage = (_Float16*)d_out;
    _Float16* xqhi = (_Float16*)((char*)d_out + 67108864);
    _Float16* xqlo = (_Float16*)((char*)d_out + 83886080);
    _Float16* xkhi = (_Float16*)((char*)d_out + 100663296);
    _Float16* xklo = (_Float16*)((char*)d_out + 117440512);

    (void)hipMemsetAsync(Pf, 0, (size_t)128 * Ln * sizeof(float2), stream);

    cvt_split_k<<<dim3(512, 2), 256, 0, stream>>>(Wq, Wqhi, Wqlo, Wk, Wkhi, Wklo, 131072);
    cvt_f16_k<<<dim3(512, 2), 256, 0, stream>>>(Wv, Wvf, Wo, Wof, 131072);

    gemm_v_k<<<dim3(256, 8), 256, 0, stream>>>(v, Wvf, bv, Vstage);

    for (int p = 0; p < 4; p++) {
        cvt_split_k<<<dim3(4096, 2), 256, 0, stream>>>(
            q + (size_t)p * 2 * Ln * Dn, xqhi, xqlo,
            kk + (size_t)p * 2 * Ln * Dn, xkhi, xklo, 1048576);
        gemm_qk_k<<<dim3(64, 8, 2), 256, 0, stream>>>(
            xqhi, xqlo, xkhi, xklo,
            Wqhi, Wqlo, Wkhi, Wklo, bq, bk, QT, KT);
        fftcorr_k<<<dim3(16, 32), 256, 0, stream>>>(QT, KT, Pf + (size_t)p * 32 * Ln);
    }
    ifftcorr_k<<<128, 256, 0, stream>>>(Pf, corr);
    topk_k<<<128, 256, 0, stream>>>(corr, topw, topi);
    agg_k<<<dim3(64, 128), 256, 0, stream>>>(Vstage, topw, topi, Y);
    gemm_o_k<<<dim3(256, 8), 256, 0, stream>>>(Y, Wof, bo, out);
}

// Round 19
// 1250.173 us; speedup vs baseline: 5.3637x; 1.1323x over previous
//
#include <hip/hip_runtime.h>

#define DEVI static __device__ __forceinline__

typedef float    f32x4 __attribute__((ext_vector_type(4)));
typedef _Float16 f16x8 __attribute__((ext_vector_type(8)));

static constexpr int Bn = 8, Ln = 4096, Dn = 1024, Hn = 16, DKn = 64;
static constexpr int TOPK = 8;
static constexpr float LO_SCALE = 2048.f, LO_INV = 1.f / 2048.f;

DEVI f32x4 mfma_f16(f16x8 a, f16x8 b, f32x4 c) {
    return __builtin_amdgcn_mfma_f32_16x16x32_f16(a, b, c, 0, 0, 0);
}

struct HL { _Float16 hi, lo; };
DEVI HL split2(float x) {
    HL r;
    r.hi = (_Float16)x;
    r.lo = (_Float16)((x - (float)r.hi) * LO_SCALE);
    return r;
}

DEVI void gload16(const void* g, void* l) {
    __builtin_amdgcn_global_load_lds(
        (const __attribute__((address_space(1))) unsigned int*)g,
        (__attribute__((address_space(3))) unsigned int*)l,
        16, 0, 0);
}

// ---------------------------------------------------------------------------
// conversion kernels (memory-bound)
// ---------------------------------------------------------------------------
__global__ __launch_bounds__(256) void cvt_split_k(
    const float* __restrict__ srcA, _Float16* __restrict__ hiA, _Float16* __restrict__ loA,
    const float* __restrict__ srcB, _Float16* __restrict__ hiB, _Float16* __restrict__ loB,
    int n8)
{
    const float* s  = blockIdx.y ? srcB : srcA;
    _Float16*    ph = blockIdx.y ? hiB  : hiA;
    _Float16*    pl = blockIdx.y ? loB  : loA;
    const int idx = blockIdx.x * 256 + threadIdx.x;
    if (idx >= n8) return;
    f32x4 x0 = *(const f32x4*)(s + (size_t)idx * 8);
    f32x4 x1 = *(const f32x4*)(s + (size_t)idx * 8 + 4);
    f16x8 h, l;
#pragma unroll
    for (int j = 0; j < 4; j++) {
        HL p0 = split2(x0[j]), p1 = split2(x1[j]);
        h[j] = p0.hi; l[j] = p0.lo;
        h[4 + j] = p1.hi; l[4 + j] = p1.lo;
    }
    *(f16x8*)(ph + (size_t)idx * 8) = h;
    *(f16x8*)(pl + (size_t)idx * 8) = l;
}

__global__ __launch_bounds__(256) void cvt_f16_k(
    const float* __restrict__ srcA, _Float16* __restrict__ dstA,
    const float* __restrict__ srcB, _Float16* __restrict__ dstB, int n8)
{
    const float* s = blockIdx.y ? srcB : srcA;
    _Float16*    d = blockIdx.y ? dstB : dstA;
    const int idx = blockIdx.x * 256 + threadIdx.x;
    if (idx >= n8) return;
    f32x4 x0 = *(const f32x4*)(s + (size_t)idx * 8);
    f32x4 x1 = *(const f32x4*)(s + (size_t)idx * 8 + 4);
    f16x8 o;
#pragma unroll
    for (int j = 0; j < 4; j++) { o[j] = (_Float16)x0[j]; o[4 + j] = (_Float16)x1[j]; }
    *(f16x8*)(d + (size_t)idx * 8) = o;
}

// ---------------------------------------------------------------------------
// m97-structure GEMM (unchanged, verified).
// ---------------------------------------------------------------------------
DEVI void stage8(const _Float16* gbase, _Float16* ltile, int w, int lane, int k0) {
#pragma unroll
    for (int c = 0; c < 2; c++) {
        const int chunk = 2 * w + c;
        const int row = chunk * 16 + (lane >> 2);
        gload16(gbase + (size_t)row * Dn + k0 + (lane & 3) * 8, ltile + chunk * 512);
    }
}

DEVI void stage16f32(const float* gbase, float* ltile, int w, int lane, int k0) {
    const int r    = lane >> 3;
    const int gsrc = (lane & 7) ^ r;
#pragma unroll
    for (int c = 0; c < 4; c++) {
        const int chunk = w * 4 + c;
        const int row = chunk * 8 + r;
        gload16(gbase + (size_t)row * Dn + k0 + gsrc * 4, ltile + chunk * 256);
    }
}

template<int MODE, bool COMP, bool AF32>
DEVI void gemm4_body(
    const void* __restrict__ A_hi, const _Float16* __restrict__ A_lo,
    const _Float16* __restrict__ W_hi, const _Float16* __restrict__ W_lo,
    const float* __restrict__ bias, void* __restrict__ out0)
{
    constexpr int ASZ = (AF32 || COMP) ? 16384 : 8192;
    __shared__ char smem[ASZ + (COMP ? 16384 : 8192)];
    float*    sAf = (float*)smem;
    _Float16* sAh = (_Float16*)smem;
    _Float16* sAl = (_Float16*)(smem + 8192);      // COMP only
    _Float16* sWh = (_Float16*)(smem + ASZ);
    _Float16* sWl = (_Float16*)(smem + ASZ + 8192);

    const int l  = threadIdx.x & 63;
    const int w  = threadIdx.x >> 6;
    const int m0 = blockIdx.x * 128;
    const int n0 = blockIdx.y * 128;
    const int wm = (w & 1) * 64, wn = (w >> 1) * 64;
    const int rr = l & 15, ko = (l >> 4) * 8, g0 = (l >> 4) * 2;

    const _Float16* Wbh = W_hi + (size_t)n0 * Dn;
    const _Float16* Wbl = COMP ? W_lo + (size_t)n0 * Dn : nullptr;

    f32x4 acc[4][4] = {};
    f32x4 accc[4][4] = {};

    for (int k0 = 0; k0 < Dn; k0 += 32) {
        if (AF32) {
            stage16f32((const float*)A_hi + (size_t)m0 * Dn, sAf, w, l, k0);
        } else {
            stage8((const _Float16*)A_hi + (size_t)m0 * Dn, sAh, w, l, k0);
            if (COMP) stage8(A_lo + (size_t)m0 * Dn, sAl, w, l, k0);
        }
        stage8(Wbh, sWh, w, l, k0);
        if (COMP) stage8(Wbl, sWl, w, l, k0);
        __syncthreads();

        f16x8 af[4], alf[4], bf[4], blf[4];
#pragma unroll
        for (int i = 0; i < 4; i++) {
            const int arow = wm + 16 * i + rr;
            if (AF32) {
                const float* rb = &sAf[arow * 32];
                f32x4 x0 = *(const f32x4*)&rb[((g0    ) ^ (arow & 7)) * 4];
                f32x4 x1 = *(const f32x4*)&rb[((g0 + 1) ^ (arow & 7)) * 4];
#pragma unroll
                for (int j = 0; j < 4; j++) {
                    af[i][j]     = (_Float16)x0[j];
                    af[i][4 + j] = (_Float16)x1[j];
                }
            } else {
                af[i] = *(const f16x8*)&sAh[arow * 32 + ko];
                if (COMP) alf[i] = *(const f16x8*)&sAl[arow * 32 + ko];
            }
            bf[i] = *(const f16x8*)&sWh[(wn + 16 * i + rr) * 32 + ko];
            if (COMP) blf[i] = *(const f16x8*)&sWl[(wn + 16 * i + rr) * 32 + ko];
        }
#pragma unroll
        for (int i = 0; i < 4; i++)
#pragma unroll
            for (int j = 0; j < 4; j++) {
                acc[i][j] = mfma_f16(af[i], bf[j], acc[i][j]);
                if (COMP) {
                    accc[i][j] = mfma_f16(alf[i], bf[j], accc[i][j]);
                    accc[i][j] = mfma_f16(af[i], blf[j], accc[i][j]);
                }
            }
        __syncthreads();
    }

    if (MODE == 2) {
        // LDS-transpose epilogue: coalesced stores to [b2][n][l] f32.
        float* sT = (float*)smem;          // 32 x 132 f32
        const int b2 = m0 >> 12;
        const int mb = m0 & (Ln - 1);
        const int npr = (wn >> 6) * 16 + rr;
#pragma unroll
        for (int j = 0; j < 4; j++) {      // FULLY UNROLLED (rule #20)
            __syncthreads();
            const float bs = bias[n0 + wn + 16 * j + rr];
#pragma unroll
            for (int i = 0; i < 4; i++)
#pragma unroll
                for (int r = 0; r < 4; r++) {
                    float v = acc[i][j][r] + accc[i][j][r] * LO_INV + bs;
                    sT[npr * 132 + wm + 16 * i + (l >> 4) * 4 + r] = v;
                }
            __syncthreads();
            const int row = threadIdx.x >> 3;
            const int cb  = (threadIdx.x & 7) * 16;
            const int n   = n0 + (row >> 4) * 64 + 16 * j + (row & 15);
            float* dst = (float*)out0 + ((size_t)(b2 * 1024 + n)) * Ln + mb + cb;
            const float* sp = &sT[row * 132 + cb];
#pragma unroll
            for (int c4 = 0; c4 < 4; c4++)
                *(f32x4*)(dst + 4 * c4) = *(const f32x4*)(sp + 4 * c4);
        }
        return;
    }

#pragma unroll
    for (int i = 0; i < 4; i++)
#pragma unroll
        for (int j = 0; j < 4; j++)
#pragma unroll
            for (int r = 0; r < 4; r++) {
                const int m = m0 + wm + 16 * i + (l >> 4) * 4 + r;
                const int n = n0 + wn + 16 * j + (l & 15);
                float v = acc[i][j][r] + bias[n];
                if (MODE == 0) {
                    ((float*)out0)[(size_t)m * Dn + n] = v;
                } else {
                    size_t idx = ((size_t)((m >> 12) * Hn + (n >> 6)) * Ln
                                  + (m & (Ln - 1))) * DKn + (n & 63);
                    ((_Float16*)out0)[idx] = (_Float16)v;
                }
            }
}

__global__ __launch_bounds__(256) void gemm_v_k(
    const float* __restrict__ xv, const _Float16* __restrict__ Wv,
    const float* __restrict__ bv, _Float16* __restrict__ Vstage)
{
    gemm4_body<1, false, true>(xv, nullptr, Wv, nullptr, bv, Vstage);
}

__global__ __launch_bounds__(256) void gemm_o_k(
    const _Float16* __restrict__ Y, const _Float16* __restrict__ Wo,
    const float* __restrict__ bo, float* __restrict__ out)
{
    gemm4_body<0, false, false>(Y, nullptr, Wo, nullptr, bo, out);
}

__global__ __launch_bounds__(256) void gemm_qk_k(
    const _Float16* __restrict__ xqhi, const _Float16* __restrict__ xqlo,
    const _Float16* __restrict__ xkhi, const _Float16* __restrict__ xklo,
    const _Float16* __restrict__ Wqhi, const _Float16* __restrict__ Wqlo,
    const _Float16* __restrict__ Wkhi, const _Float16* __restrict__ Wklo,
    const float* __restrict__ bq, const float* __restrict__ bk,
    float* __restrict__ QT, float* __restrict__ KT)
{
    if (blockIdx.z == 0)
        gemm4_body<2, true, false>(xqhi, xqlo, Wqhi, Wqlo, bq, QT);
    else
        gemm4_body<2, true, false>(xkhi, xklo, Wkhi, Wklo, bk, KT);
}

// ---------------------------------------------------------------------------
// FFT-based correlation, v3: 512 threads/block (occupancy fix -- LDS caps at
// 2 blocks/CU; 512 thr doubles waves/CU 8->16). Same verified math.
//  - two-reals pack: FFT(q + i*k) once; unpack by conjugate symmetry.
//  - pad i + (i>>4) + (i>>8): radix-4 taps land on distinct bank groups.
// ---------------------------------------------------------------------------
DEVI int FPAD(int i) { return i + (i >> 4) + (i >> 8); }

DEVI float2 cmulf(float2 a, float2 b) {
    return make_float2(a.x * b.x - a.y * b.y, a.x * b.y + a.y * b.x);
}

DEVI void fft_pass(const float2* in, float2* out, int ls2, int tid) {
    const int Ns = 1 << ls2;
#pragma unroll
    for (int r = 0; r < 2; r++) {
        const int j = tid + r * 512;          // 0..1023
        float2 v0 = in[FPAD(j)];
        float2 v1 = in[FPAD(j + 1024)];
        float2 v2 = in[FPAD(j + 2048)];
        float2 v3 = in[FPAD(j + 3072)];
        const int p = j & (Ns - 1);
        const float ang = -6.283185307179586f * (float)p / (4.f * (float)Ns);
        float sn, cs;
        __sincosf(ang, &sn, &cs);
        const float2 w1 = make_float2(cs, sn);
        const float2 w2 = cmulf(w1, w1);
        const float2 w3 = cmulf(w2, w1);
        v1 = cmulf(v1, w1); v2 = cmulf(v2, w2); v3 = cmulf(v3, w3);
        const float2 t0 = make_float2(v0.x + v2.x, v0.y + v2.y);
        const float2 t1 = make_float2(v0.x - v2.x, v0.y - v2.y);
        const float2 t2 = make_float2(v1.x + v3.x, v1.y + v3.y);
        const float2 t3 = make_float2(v1.x - v3.x, v1.y - v3.y);
        const float2 t3i = make_float2(t3.y, -t3.x);
        const int db = ((j >> ls2) << (ls2 + 2)) | p;
        out[FPAD(db)]          = make_float2(t0.x + t2.x, t0.y + t2.y);
        out[FPAD(db + Ns)]     = make_float2(t1.x + t3i.x, t1.y + t3i.y);
        out[FPAD(db + 2 * Ns)] = make_float2(t0.x - t2.x, t0.y - t2.y);
        out[FPAD(db + 3 * Ns)] = make_float2(t1.x - t3i.x, t1.y - t3i.y);
    }
}

DEVI void fft4096(float2* A, float2* B, int tid) {
    __syncthreads();
    fft_pass(A, B, 0, tid);  __syncthreads();
    fft_pass(B, A, 2, tid);  __syncthreads();
    fft_pass(A, B, 4, tid);  __syncthreads();
    fft_pass(B, A, 6, tid);  __syncthreads();
    fft_pass(A, B, 8, tid);  __syncthreads();
    fft_pass(B, A, 10, tid); __syncthreads();
}

__global__ __launch_bounds__(512) void fftcorr_k(
    const float* __restrict__ QT, const float* __restrict__ KT,
    float2* __restrict__ Pf)
{
    __shared__ float2 A[4368], B[4368];
    const int tid = threadIdx.x;
    const int bh  = blockIdx.y;
    const int d0  = blockIdx.x * 4;
    float2 acc[8];
#pragma unroll
    for (int i = 0; i < 8; i++) acc[i] = make_float2(0.f, 0.f);

    for (int dd = 0; dd < 4; dd++) {
        const int d = d0 + dd;
        const float* qc = QT + ((size_t)bh * 64 + d) * Ln;
        const float* kc = KT + ((size_t)bh * 64 + d) * Ln;
#pragma unroll
        for (int i = 0; i < 8; i++) {
            const int row = tid + 512 * i;
            A[FPAD(row)] = make_float2(qc[row], kc[row]);   // z = q + i*k
        }
        fft4096(A, B, tid);
        // Qf[t] = (Z[t]+conj(Z[-t]))/2 ; Kf[t] = -i(Z[t]-conj(Z[-t]))/2
        // acc += Qf * conj(Kf)
#pragma unroll
        for (int i = 0; i < 8; i++) {
            const int t  = tid + 512 * i;
            const int tm = (Ln - t) & (Ln - 1);
            float2 Zt = A[FPAD(t)];
            float2 Zm = A[FPAD(tm)];
            const float qr = 0.5f * (Zt.x + Zm.x);
            const float qi = 0.5f * (Zt.y - Zm.y);
            const float kr = 0.5f * (Zt.y + Zm.y);
            const float ki = 0.5f * (Zm.x - Zt.x);
            acc[i].x += qr * kr + qi * ki;
            acc[i].y += qi * kr - qr * ki;
        }
        __syncthreads();
    }
    float2* P = Pf + (size_t)bh * Ln;
#pragma unroll
    for (int i = 0; i < 8; i++) {
        atomicAdd(&P[tid + 512 * i].x, acc[i].x);
        atomicAdd(&P[tid + 512 * i].y, acc[i].y);
    }
}

__global__ __launch_bounds__(512) void ifftcorr_k(
    const float2* __restrict__ Pf, float* __restrict__ corr)
{
    __shared__ float2 A[4368], B[4368];
    const int tid = threadIdx.x;
    const int bh = blockIdx.x;
    const float2* P = Pf + (size_t)bh * Ln;
#pragma unroll
    for (int i = 0; i < 8; i++) {
        float2 v = P[tid + 512 * i];
        A[FPAD(tid + 512 * i)] = make_float2(v.x, -v.y);
    }
    fft4096(A, B, tid);
#pragma unroll
    for (int i = 0; i < 8; i++)
        corr[(size_t)bh * Ln + tid + 512 * i] =
            A[FPAD(tid + 512 * i)].x * (1.f / 4096.f);
}

// ---------------------------------------------------------------------------
// Top-8 + softmax per (b,h) row of corr (raw sums; /64 before softmax).
// ---------------------------------------------------------------------------
__global__ __launch_bounds__(256) void topk_k(
    const float* __restrict__ corr, float* __restrict__ top_w,
    int* __restrict__ top_idx)
{
    __shared__ float vals[Ln];
    __shared__ float rv[256];
    __shared__ int   ri[256];
    __shared__ float sel_v[TOPK];
    __shared__ int   sel_i[TOPK];
    const int bh = blockIdx.x;
    const float* c = corr + (size_t)bh * Ln;
    for (int i = threadIdx.x; i < Ln; i += 256) vals[i] = c[i];
    __syncthreads();

    for (int it = 0; it < TOPK; it++) {
        float bvv = -1e30f; int bi = 0;
        const int base = threadIdx.x * 16;
#pragma unroll
        for (int j = 0; j < 16; j++) {
            float v = vals[base + j];
            if (v > bvv) { bvv = v; bi = base + j; }
        }
        rv[threadIdx.x] = bvv; ri[threadIdx.x] = bi;
        __syncthreads();
        if (threadIdx.x == 0) {
            float gv = rv[0]; int gi = ri[0];
            for (int t = 1; t < 256; t++)
                if (rv[t] > gv) { gv = rv[t]; gi = ri[t]; }
            sel_v[it] = gv; sel_i[it] = gi;
            vals[gi] = -1e30f;
        }
        __syncthreads();
    }
    if (threadIdx.x == 0) {
        float e[TOPK], s = 0.f;
        for (int i = 0; i < TOPK; i++) {
            e[i] = expf((sel_v[i] - sel_v[0]) * (1.f / 64.f));
            s += e[i];
        }
        for (int i = 0; i < TOPK; i++) {
            top_w[bh * TOPK + i]   = e[i] / s;
            top_idx[bh * TOPK + i] = sel_i[i];
        }
    }
}

// ---------------------------------------------------------------------------
// Aggregation: Y[b][t][h*64+d] = sum_i w_i * V[b][h][(t-idx_i)&4095][d]
// ---------------------------------------------------------------------------
__global__ __launch_bounds__(256) void agg_k(
    const _Float16* __restrict__ V /* [B][H][L][64] */,
    const float* __restrict__ top_w, const int* __restrict__ top_idx,
    _Float16* __restrict__ Y /* [B][L][1024] */)
{
    __shared__ float w_s[TOPK];
    __shared__ int   i_s[TOPK];
    const int bh   = blockIdx.y;
    const int b    = bh >> 4, h = bh & 15;
    const int tloc = threadIdx.x >> 2;
    const int c16  = (threadIdx.x & 3) * 16;
    const int t    = blockIdx.x * 64 + tloc;
    if (threadIdx.x < TOPK) {
        w_s[threadIdx.x] = top_w[bh * TOPK + threadIdx.x];
        i_s[threadIdx.x] = top_idx[bh * TOPK + threadIdx.x];
    }
    __syncthreads();

    const _Float16* Vb = V + (size_t)bh * Ln * DKn;
    float acc[16] = {};
#pragma unroll
    for (int i = 0; i < TOPK; i++) {
        const int src = (t - i_s[i]) & (Ln - 1);
        const _Float16* p = Vb + (size_t)src * DKn + c16;
        f16x8 v0 = *(const f16x8*)(p);
        f16x8 v1 = *(const f16x8*)(p + 8);
        const float wgt = w_s[i];
#pragma unroll
        for (int j = 0; j < 8; j++) acc[j]     += wgt * (float)v0[j];
#pragma unroll
        for (int j = 0; j < 8; j++) acc[8 + j] += wgt * (float)v1[j];
    }
    f16x8 o0, o1;
#pragma unroll
    for (int j = 0; j < 8; j++) { o0[j] = (_Float16)acc[j]; o1[j] = (_Float16)acc[8 + j]; }
    const size_t oidx = ((size_t)(b * Ln + t)) * Dn + h * DKn + c16;
    *(f16x8*)(Y + oidx)     = o0;
    *(f16x8*)(Y + oidx + 8) = o1;
}

// ---------------------------------------------------------------------------
extern "C" void kernel_launch(void* const* d_in, const int* in_sizes, int n_in,
                              void* d_out, int out_size, void* d_ws, size_t ws_size,
                              hipStream_t stream)
{
    const float* q  = (const float*)d_in[0];
    const float* kk = (const float*)d_in[1];
    const float* v  = (const float*)d_in[2];
    const float* Wq = (const float*)d_in[3];
    const float* bq = (const float*)d_in[4];
    const float* Wk = (const float*)d_in[5];
    const float* bk = (const float*)d_in[6];
    const float* Wv = (const float*)d_in[7];
    const float* bv = (const float*)d_in[8];
    const float* Wo = (const float*)d_in[9];
    const float* bo = (const float*)d_in[10];
    float* out = (float*)d_out;

    char* ws = (char*)d_ws;
    if (ws_size < 85991424ull) return;
    float*    QT   = (float*)(ws);
    float*    KT   = (float*)(ws + 33554432);
    _Float16* Y    = (_Float16*)(ws);
    float*    corr = (float*)(ws + 67108864);
    float*    topw = (float*)(ws + 69206016);
    int*      topi = (int*)(ws + 69210112);
    _Float16* Wqhi = (_Float16*)(ws + 69214208);
    _Float16* Wqlo = (_Float16*)(ws + 71311360);
    _Float16* Wkhi = (_Float16*)(ws + 73408512);
    _Float16* Wklo = (_Float16*)(ws + 75505664);
    _Float16* Wvf  = (_Float16*)(ws + 77602816);
    _Float16* Wof  = (_Float16*)(ws + 79699968);
    float2*   Pf   = (float2*)(ws + 81797120);

    _Float16* Vstage = (_Float16*)d_out;
    _Float16* xqhi = (_Float16*)((char*)d_out + 67108864);
    _Float16* xqlo = (_Float16*)((char*)d_out + 83886080);
    _Float16* xkhi = (_Float16*)((char*)d_out + 100663296);
    _Float16* xklo = (_Float16*)((char*)d_out + 117440512);

    (void)hipMemsetAsync(Pf, 0, (size_t)128 * Ln * sizeof(float2), stream);

    cvt_split_k<<<dim3(512, 2), 256, 0, stream>>>(Wq, Wqhi, Wqlo, Wk, Wkhi, Wklo, 131072);
    cvt_f16_k<<<dim3(512, 2), 256, 0, stream>>>(Wv, Wvf, Wo, Wof, 131072);

    gemm_v_k<<<dim3(256, 8), 256, 0, stream>>>(v, Wvf, bv, Vstage);

    for (int p = 0; p < 4; p++) {
        cvt_split_k<<<dim3(4096, 2), 256, 0, stream>>>(
            q + (size_t)p * 2 * Ln * Dn, xqhi, xqlo,
            kk + (size_t)p * 2 * Ln * Dn, xkhi, xklo, 1048576);
        gemm_qk_k<<<dim3(64, 8, 2), 256, 0, stream>>>(
            xqhi, xqlo, xkhi, xklo,
            Wqhi, Wqlo, Wkhi, Wklo, bq, bk, QT, KT);
        fftcorr_k<<<dim3(16, 32), 512, 0, stream>>>(QT, KT, Pf + (size_t)p * 32 * Ln);
    }
    ifftcorr_k<<<128, 512, 0, stream>>>(Pf, corr);
    topk_k<<<128, 256, 0, stream>>>(corr, topw, topi);
    agg_k<<<dim3(64, 128), 256, 0, stream>>>(Vstage, topw, topi, Y);
    gemm_o_k<<<dim3(256, 8), 256, 0, stream>>>(Y, Wof, bo, out);
}

// Round 20
// 1242.445 us; speedup vs baseline: 5.3971x; 1.0062x over previous
//
#include <hip/hip_runtime.h>

#define DEVI static __device__ __forceinline__

typedef float    f32x4 __attribute__((ext_vector_type(4)));
typedef _Float16 f16x8 __attribute__((ext_vector_type(8)));

static constexpr int Bn = 8, Ln = 4096, Dn = 1024, Hn = 16, DKn = 64;
static constexpr int TOPK = 8;
static constexpr float LO_SCALE = 2048.f, LO_INV = 1.f / 2048.f;

DEVI f32x4 mfma_f16(f16x8 a, f16x8 b, f32x4 c) {
    return __builtin_amdgcn_mfma_f32_16x16x32_f16(a, b, c, 0, 0, 0);
}

struct HL { _Float16 hi, lo; };
DEVI HL split2(float x) {
    HL r;
    r.hi = (_Float16)x;
    r.lo = (_Float16)((x - (float)r.hi) * LO_SCALE);
    return r;
}

DEVI void gload16(const void* g, void* l) {
    __builtin_amdgcn_global_load_lds(
        (const __attribute__((address_space(1))) unsigned int*)g,
        (__attribute__((address_space(3))) unsigned int*)l,
        16, 0, 0);
}

// ---------------------------------------------------------------------------
// conversion kernels (memory-bound)
// ---------------------------------------------------------------------------
__global__ __launch_bounds__(256) void cvt_split_k(
    const float* __restrict__ srcA, _Float16* __restrict__ hiA, _Float16* __restrict__ loA,
    const float* __restrict__ srcB, _Float16* __restrict__ hiB, _Float16* __restrict__ loB,
    int n8)
{
    const float* s  = blockIdx.y ? srcB : srcA;
    _Float16*    ph = blockIdx.y ? hiB  : hiA;
    _Float16*    pl = blockIdx.y ? loB  : loA;
    const int idx = blockIdx.x * 256 + threadIdx.x;
    if (idx >= n8) return;
    f32x4 x0 = *(const f32x4*)(s + (size_t)idx * 8);
    f32x4 x1 = *(const f32x4*)(s + (size_t)idx * 8 + 4);
    f16x8 h, l;
#pragma unroll
    for (int j = 0; j < 4; j++) {
        HL p0 = split2(x0[j]), p1 = split2(x1[j]);
        h[j] = p0.hi; l[j] = p0.lo;
        h[4 + j] = p1.hi; l[4 + j] = p1.lo;
    }
    *(f16x8*)(ph + (size_t)idx * 8) = h;
    *(f16x8*)(pl + (size_t)idx * 8) = l;
}

__global__ __launch_bounds__(256) void cvt_f16_k(
    const float* __restrict__ srcA, _Float16* __restrict__ dstA,
    const float* __restrict__ srcB, _Float16* __restrict__ dstB, int n8)
{
    const float* s = blockIdx.y ? srcB : srcA;
    _Float16*    d = blockIdx.y ? dstB : dstA;
    const int idx = blockIdx.x * 256 + threadIdx.x;
    if (idx >= n8) return;
    f32x4 x0 = *(const f32x4*)(s + (size_t)idx * 8);
    f32x4 x1 = *(const f32x4*)(s + (size_t)idx * 8 + 4);
    f16x8 o;
#pragma unroll
    for (int j = 0; j < 4; j++) { o[j] = (_Float16)x0[j]; o[4 + j] = (_Float16)x1[j]; }
    *(f16x8*)(d + (size_t)idx * 8) = o;
}

// ---------------------------------------------------------------------------
// m97-structure GEMM + XOR-swizzled f16 staging (kills the 8-way 64B-stride
// bank conflict on fragment ds_read_b128; round-19 counters: 8.4M conflicts).
// Swizzle (both-sides rule): stage8 pre-swizzles the GLOBAL source granule
// (gsrc = g ^ ((row>>1)&3)), LDS dest stays linear; fragment reads XOR the
// same involution. Post-swizzle: 16 lanes cover all 8 16B-slots 2-way (free).
// ---------------------------------------------------------------------------
DEVI void stage8(const _Float16* gbase, _Float16* ltile, int w, int lane, int k0) {
    const int gsrc = (lane & 3) ^ ((lane >> 3) & 3);   // g ^ ((row>>1)&3)
#pragma unroll
    for (int c = 0; c < 2; c++) {
        const int chunk = 2 * w + c;
        const int row = chunk * 16 + (lane >> 2);
        gload16(gbase + (size_t)row * Dn + k0 + gsrc * 8, ltile + chunk * 512);
    }
}

DEVI void stage16f32(const float* gbase, float* ltile, int w, int lane, int k0) {
    const int r    = lane >> 3;
    const int gsrc = (lane & 7) ^ r;
#pragma unroll
    for (int c = 0; c < 4; c++) {
        const int chunk = w * 4 + c;
        const int row = chunk * 8 + r;
        gload16(gbase + (size_t)row * Dn + k0 + gsrc * 4, ltile + chunk * 256);
    }
}

template<int MODE, bool COMP, bool AF32>
DEVI void gemm4_body(
    const void* __restrict__ A_hi, const _Float16* __restrict__ A_lo,
    const _Float16* __restrict__ W_hi, const _Float16* __restrict__ W_lo,
    const float* __restrict__ bias, void* __restrict__ out0)
{
    constexpr int ASZ = (AF32 || COMP) ? 16384 : 8192;
    __shared__ char smem[ASZ + (COMP ? 16384 : 8192)];
    float*    sAf = (float*)smem;
    _Float16* sAh = (_Float16*)smem;
    _Float16* sAl = (_Float16*)(smem + 8192);      // COMP only
    _Float16* sWh = (_Float16*)(smem + ASZ);
    _Float16* sWl = (_Float16*)(smem + ASZ + 8192);

    const int l  = threadIdx.x & 63;
    const int w  = threadIdx.x >> 6;
    const int m0 = blockIdx.x * 128;
    const int n0 = blockIdx.y * 128;
    const int wm = (w & 1) * 64, wn = (w >> 1) * 64;
    const int rr = l & 15, g0 = (l >> 4) * 2;
    // swizzled f16 fragment granule offset: ((l>>4) ^ ((rr>>1)&3)) * 8
    const int gsw = (((l >> 4) ^ ((rr >> 1) & 3)) * 8);

    const _Float16* Wbh = W_hi + (size_t)n0 * Dn;
    const _Float16* Wbl = COMP ? W_lo + (size_t)n0 * Dn : nullptr;

    f32x4 acc[4][4] = {};
    f32x4 accc[4][4] = {};

    for (int k0 = 0; k0 < Dn; k0 += 32) {
        if (AF32) {
            stage16f32((const float*)A_hi + (size_t)m0 * Dn, sAf, w, l, k0);
        } else {
            stage8((const _Float16*)A_hi + (size_t)m0 * Dn, sAh, w, l, k0);
            if (COMP) stage8(A_lo + (size_t)m0 * Dn, sAl, w, l, k0);
        }
        stage8(Wbh, sWh, w, l, k0);
        if (COMP) stage8(Wbl, sWl, w, l, k0);
        __syncthreads();

        f16x8 af[4], alf[4], bf[4], blf[4];
#pragma unroll
        for (int i = 0; i < 4; i++) {
            const int arow = wm + 16 * i + rr;
            if (AF32) {
                const float* rb = &sAf[arow * 32];
                f32x4 x0 = *(const f32x4*)&rb[((g0    ) ^ (arow & 7)) * 4];
                f32x4 x1 = *(const f32x4*)&rb[((g0 + 1) ^ (arow & 7)) * 4];
#pragma unroll
                for (int j = 0; j < 4; j++) {
                    af[i][j]     = (_Float16)x0[j];
                    af[i][4 + j] = (_Float16)x1[j];
                }
            } else {
                af[i] = *(const f16x8*)&sAh[arow * 32 + gsw];
                if (COMP) alf[i] = *(const f16x8*)&sAl[arow * 32 + gsw];
            }
            const int wrow = wn + 16 * i + rr;
            bf[i] = *(const f16x8*)&sWh[wrow * 32 + gsw];
            if (COMP) blf[i] = *(const f16x8*)&sWl[wrow * 32 + gsw];
        }
#pragma unroll
        for (int i = 0; i < 4; i++)
#pragma unroll
            for (int j = 0; j < 4; j++) {
                acc[i][j] = mfma_f16(af[i], bf[j], acc[i][j]);
                if (COMP) {
                    accc[i][j] = mfma_f16(alf[i], bf[j], accc[i][j]);
                    accc[i][j] = mfma_f16(af[i], blf[j], accc[i][j]);
                }
            }
        __syncthreads();
    }

    if (MODE == 2) {
        // LDS-transpose epilogue: coalesced stores to [b2][n][l] f32.
        float* sT = (float*)smem;          // 32 x 132 f32
        const int b2 = m0 >> 12;
        const int mb = m0 & (Ln - 1);
        const int npr = (wn >> 6) * 16 + rr;
#pragma unroll
        for (int j = 0; j < 4; j++) {      // FULLY UNROLLED (rule #20)
            __syncthreads();
            const float bs = bias[n0 + wn + 16 * j + rr];
#pragma unroll
            for (int i = 0; i < 4; i++)
#pragma unroll
                for (int r = 0; r < 4; r++) {
                    float v = acc[i][j][r] + accc[i][j][r] * LO_INV + bs;
                    sT[npr * 132 + wm + 16 * i + (l >> 4) * 4 + r] = v;
                }
            __syncthreads();
            const int row = threadIdx.x >> 3;
            const int cb  = (threadIdx.x & 7) * 16;
            const int n   = n0 + (row >> 4) * 64 + 16 * j + (row & 15);
            float* dst = (float*)out0 + ((size_t)(b2 * 1024 + n)) * Ln + mb + cb;
            const float* sp = &sT[row * 132 + cb];
#pragma unroll
            for (int c4 = 0; c4 < 4; c4++)
                *(f32x4*)(dst + 4 * c4) = *(const f32x4*)(sp + 4 * c4);
        }
        return;
    }

#pragma unroll
    for (int i = 0; i < 4; i++)
#pragma unroll
        for (int j = 0; j < 4; j++)
#pragma unroll
            for (int r = 0; r < 4; r++) {
                const int m = m0 + wm + 16 * i + (l >> 4) * 4 + r;
                const int n = n0 + wn + 16 * j + (l & 15);
                float v = acc[i][j][r] + bias[n];
                if (MODE == 0) {
                    ((float*)out0)[(size_t)m * Dn + n] = v;
                } else {
                    size_t idx = ((size_t)((m >> 12) * Hn + (n >> 6)) * Ln
                                  + (m & (Ln - 1))) * DKn + (n & 63);
                    ((_Float16*)out0)[idx] = (_Float16)v;
                }
            }
}

__global__ __launch_bounds__(256) void gemm_v_k(
    const float* __restrict__ xv, const _Float16* __restrict__ Wv,
    const float* __restrict__ bv, _Float16* __restrict__ Vstage)
{
    gemm4_body<1, false, true>(xv, nullptr, Wv, nullptr, bv, Vstage);
}

__global__ __launch_bounds__(256) void gemm_o_k(
    const _Float16* __restrict__ Y, const _Float16* __restrict__ Wo,
    const float* __restrict__ bo, float* __restrict__ out)
{
    gemm4_body<0, false, false>(Y, nullptr, Wo, nullptr, bo, out);
}

__global__ __launch_bounds__(256) void gemm_qk_k(
    const _Float16* __restrict__ xqhi, const _Float16* __restrict__ xqlo,
    const _Float16* __restrict__ xkhi, const _Float16* __restrict__ xklo,
    const _Float16* __restrict__ Wqhi, const _Float16* __restrict__ Wqlo,
    const _Float16* __restrict__ Wkhi, const _Float16* __restrict__ Wklo,
    const float* __restrict__ bq, const float* __restrict__ bk,
    float* __restrict__ QT, float* __restrict__ KT)
{
    if (blockIdx.z == 0)
        gemm4_body<2, true, false>(xqhi, xqlo, Wqhi, Wqlo, bq, QT);
    else
        gemm4_body<2, true, false>(xkhi, xklo, Wkhi, Wklo, bk, KT);
}

// ---------------------------------------------------------------------------
// FFT-based correlation (512 threads/block, two-reals pack, verified).
// ---------------------------------------------------------------------------
DEVI int FPAD(int i) { return i + (i >> 4) + (i >> 8); }

DEVI float2 cmulf(float2 a, float2 b) {
    return make_float2(a.x * b.x - a.y * b.y, a.x * b.y + a.y * b.x);
}

DEVI void fft_pass(const float2* in, float2* out, int ls2, int tid) {
    const int Ns = 1 << ls2;
#pragma unroll
    for (int r = 0; r < 2; r++) {
        const int j = tid + r * 512;
        float2 v0 = in[FPAD(j)];
        float2 v1 = in[FPAD(j + 1024)];
        float2 v2 = in[FPAD(j + 2048)];
        float2 v3 = in[FPAD(j + 3072)];
        const int p = j & (Ns - 1);
        const float ang = -6.283185307179586f * (float)p / (4.f * (float)Ns);
        float sn, cs;
        __sincosf(ang, &sn, &cs);
        const float2 w1 = make_float2(cs, sn);
        const float2 w2 = cmulf(w1, w1);
        const float2 w3 = cmulf(w2, w1);
        v1 = cmulf(v1, w1); v2 = cmulf(v2, w2); v3 = cmulf(v3, w3);
        const float2 t0 = make_float2(v0.x + v2.x, v0.y + v2.y);
        const float2 t1 = make_float2(v0.x - v2.x, v0.y - v2.y);
        const float2 t2 = make_float2(v1.x + v3.x, v1.y + v3.y);
        const float2 t3 = make_float2(v1.x - v3.x, v1.y - v3.y);
        const float2 t3i = make_float2(t3.y, -t3.x);
        const int db = ((j >> ls2) << (ls2 + 2)) | p;
        out[FPAD(db)]          = make_float2(t0.x + t2.x, t0.y + t2.y);
        out[FPAD(db + Ns)]     = make_float2(t1.x + t3i.x, t1.y + t3i.y);
        out[FPAD(db + 2 * Ns)] = make_float2(t0.x - t2.x, t0.y - t2.y);
        out[FPAD(db + 3 * Ns)] = make_float2(t1.x - t3i.x, t1.y - t3i.y);
    }
}

DEVI void fft4096(float2* A, float2* B, int tid) {
    __syncthreads();
    fft_pass(A, B, 0, tid);  __syncthreads();
    fft_pass(B, A, 2, tid);  __syncthreads();
    fft_pass(A, B, 4, tid);  __syncthreads();
    fft_pass(B, A, 6, tid);  __syncthreads();
    fft_pass(A, B, 8, tid);  __syncthreads();
    fft_pass(B, A, 10, tid); __syncthreads();
}

__global__ __launch_bounds__(512) void fftcorr_k(
    const float* __restrict__ QT, const float* __restrict__ KT,
    float2* __restrict__ Pf)
{
    __shared__ float2 A[4368], B[4368];
    const int tid = threadIdx.x;
    const int bh  = blockIdx.y;
    const int d0  = blockIdx.x * 4;
    float2 acc[8];
#pragma unroll
    for (int i = 0; i < 8; i++) acc[i] = make_float2(0.f, 0.f);

    for (int dd = 0; dd < 4; dd++) {
        const int d = d0 + dd;
        const float* qc = QT + ((size_t)bh * 64 + d) * Ln;
        const float* kc = KT + ((size_t)bh * 64 + d) * Ln;
#pragma unroll
        for (int i = 0; i < 8; i++) {
            const int row = tid + 512 * i;
            A[FPAD(row)] = make_float2(qc[row], kc[row]);
        }
        fft4096(A, B, tid);
#pragma unroll
        for (int i = 0; i < 8; i++) {
            const int t  = tid + 512 * i;
            const int tm = (Ln - t) & (Ln - 1);
            float2 Zt = A[FPAD(t)];
            float2 Zm = A[FPAD(tm)];
            const float qr = 0.5f * (Zt.x + Zm.x);
            const float qi = 0.5f * (Zt.y - Zm.y);
            const float kr = 0.5f * (Zt.y + Zm.y);
            const float ki = 0.5f * (Zm.x - Zt.x);
            acc[i].x += qr * kr + qi * ki;
            acc[i].y += qi * kr - qr * ki;
        }
        __syncthreads();
    }
    float2* P = Pf + (size_t)bh * Ln;
#pragma unroll
    for (int i = 0; i < 8; i++) {
        atomicAdd(&P[tid + 512 * i].x, acc[i].x);
        atomicAdd(&P[tid + 512 * i].y, acc[i].y);
    }
}

__global__ __launch_bounds__(512) void ifftcorr_k(
    const float2* __restrict__ Pf, float* __restrict__ corr)
{
    __shared__ float2 A[4368], B[4368];
    const int tid = threadIdx.x;
    const int bh = blockIdx.x;
    const float2* P = Pf + (size_t)bh * Ln;
#pragma unroll
    for (int i = 0; i < 8; i++) {
        float2 v = P[tid + 512 * i];
        A[FPAD(tid + 512 * i)] = make_float2(v.x, -v.y);
    }
    fft4096(A, B, tid);
#pragma unroll
    for (int i = 0; i < 8; i++)
        corr[(size_t)bh * Ln + tid + 512 * i] =
            A[FPAD(tid + 512 * i)].x * (1.f / 4096.f);
}

// ---------------------------------------------------------------------------
// Top-8 + softmax per (b,h) row of corr (raw sums; /64 before softmax).
// ---------------------------------------------------------------------------
__global__ __launch_bounds__(256) void topk_k(
    const float* __restrict__ corr, float* __restrict__ top_w,
    int* __restrict__ top_idx)
{
    __shared__ float vals[Ln];
    __shared__ float rv[256];
    __shared__ int   ri[256];
    __shared__ float sel_v[TOPK];
    __shared__ int   sel_i[TOPK];
    const int bh = blockIdx.x;
    const float* c = corr + (size_t)bh * Ln;
    for (int i = threadIdx.x; i < Ln; i += 256) vals[i] = c[i];
    __syncthreads();

    for (int it = 0; it < TOPK; it++) {
        float bvv = -1e30f; int bi = 0;
        const int base = threadIdx.x * 16;
#pragma unroll
        for (int j = 0; j < 16; j++) {
            float v = vals[base + j];
            if (v > bvv) { bvv = v; bi = base + j; }
        }
        rv[threadIdx.x] = bvv; ri[threadIdx.x] = bi;
        __syncthreads();
        if (threadIdx.x == 0) {
            float gv = rv[0]; int gi = ri[0];
            for (int t = 1; t < 256; t++)
                if (rv[t] > gv) { gv = rv[t]; gi = ri[t]; }
            sel_v[it] = gv; sel_i[it] = gi;
            vals[gi] = -1e30f;
        }
        __syncthreads();
    }
    if (threadIdx.x == 0) {
        float e[TOPK], s = 0.f;
        for (int i = 0; i < TOPK; i++) {
            e[i] = expf((sel_v[i] - sel_v[0]) * (1.f / 64.f));
            s += e[i];
        }
        for (int i = 0; i < TOPK; i++) {
            top_w[bh * TOPK + i]   = e[i] / s;
            top_idx[bh * TOPK + i] = sel_i[i];
        }
    }
}

// ---------------------------------------------------------------------------
// Aggregation: Y[b][t][h*64+d] = sum_i w_i * V[b][h][(t-idx_i)&4095][d]
// ---------------------------------------------------------------------------
__global__ __launch_bounds__(256) void agg_k(
    const _Float16* __restrict__ V /* [B][H][L][64] */,
    const float* __restrict__ top_w, const int* __restrict__ top_idx,
    _Float16* __restrict__ Y /* [B][L][1024] */)
{
    __shared__ float w_s[TOPK];
    __shared__ int   i_s[TOPK];
    const int bh   = blockIdx.y;
    const int b    = bh >> 4, h = bh & 15;
    const int tloc = threadIdx.x >> 2;
    const int c16  = (threadIdx.x & 3) * 16;
    const int t    = blockIdx.x * 64 + tloc;
    if (threadIdx.x < TOPK) {
        w_s[threadIdx.x] = top_w[bh * TOPK + threadIdx.x];
        i_s[threadIdx.x] = top_idx[bh * TOPK + threadIdx.x];
    }
    __syncthreads();

    const _Float16* Vb = V + (size_t)bh * Ln * DKn;
    float acc[16] = {};
#pragma unroll
    for (int i = 0; i < TOPK; i++) {
        const int src = (t - i_s[i]) & (Ln - 1);
        const _Float16* p = Vb + (size_t)src * DKn + c16;
        f16x8 v0 = *(const f16x8*)(p);
        f16x8 v1 = *(const f16x8*)(p + 8);
        const float wgt = w_s[i];
#pragma unroll
        for (int j = 0; j < 8; j++) acc[j]     += wgt * (float)v0[j];
#pragma unroll
        for (int j = 0; j < 8; j++) acc[8 + j] += wgt * (float)v1[j];
    }
    f16x8 o0, o1;
#pragma unroll
    for (int j = 0; j < 8; j++) { o0[j] = (_Float16)acc[j]; o1[j] = (_Float16)acc[8 + j]; }
    const size_t oidx = ((size_t)(b * Ln + t)) * Dn + h * DKn + c16;
    *(f16x8*)(Y + oidx)     = o0;
    *(f16x8*)(Y + oidx + 8) = o1;
}

// ---------------------------------------------------------------------------
extern "C" void kernel_launch(void* const* d_in, const int* in_sizes, int n_in,
                              void* d_out, int out_size, void* d_ws, size_t ws_size,
                              hipStream_t stream)
{
    const float* q  = (const float*)d_in[0];
    const float* kk = (const float*)d_in[1];
    const float* v  = (const float*)d_in[2];
    const float* Wq = (const float*)d_in[3];
    const float* bq = (const float*)d_in[4];
    const float* Wk = (const float*)d_in[5];
    const float* bk = (const float*)d_in[6];
    const float* Wv = (const float*)d_in[7];
    const float* bv = (const float*)d_in[8];
    const float* Wo = (const float*)d_in[9];
    const float* bo = (const float*)d_in[10];
    float* out = (float*)d_out;

    char* ws = (char*)d_ws;
    if (ws_size < 85991424ull) return;
    float*    QT   = (float*)(ws);
    float*    KT   = (float*)(ws + 33554432);
    _Float16* Y    = (_Float16*)(ws);
    float*    corr = (float*)(ws + 67108864);
    float*    topw = (float*)(ws + 69206016);
    int*      topi = (int*)(ws + 69210112);
    _Float16* Wqhi = (_Float16*)(ws + 69214208);
    _Float16* Wqlo = (_Float16*)(ws + 71311360);
    _Float16* Wkhi = (_Float16*)(ws + 73408512);
    _Float16* Wklo = (_Float16*)(ws + 75505664);
    _Float16* Wvf  = (_Float16*)(ws + 77602816);
    _Float16* Wof  = (_Float16*)(ws + 79699968);
    float2*   Pf   = (float2*)(ws + 81797120);

    _Float16* Vstage = (_Float16*)d_out;
    _Float16* xqhi = (_Float16*)((char*)d_out + 67108864);
    _Float16* xqlo = (_Float16*)((char*)d_out + 83886080);
    _Float16* xkhi = (_Float16*)((char*)d_out + 100663296);
    _Float16* xklo = (_Float16*)((char*)d_out + 117440512);

    (void)hipMemsetAsync(Pf, 0, (size_t)128 * Ln * sizeof(float2), stream);

    cvt_split_k<<<dim3(512, 2), 256, 0, stream>>>(Wq, Wqhi, Wqlo, Wk, Wkhi, Wklo, 131072);
    cvt_f16_k<<<dim3(512, 2), 256, 0, stream>>>(Wv, Wvf, Wo, Wof, 131072);

    gemm_v_k<<<dim3(256, 8), 256, 0, stream>>>(v, Wvf, bv, Vstage);

    for (int p = 0; p < 4; p++) {
        cvt_split_k<<<dim3(4096, 2), 256, 0, stream>>>(
            q + (size_t)p * 2 * Ln * Dn, xqhi, xqlo,
            kk + (size_t)p * 2 * Ln * Dn, xkhi, xklo, 1048576);
        gemm_qk_k<<<dim3(64, 8, 2), 256, 0, stream>>>(
            xqhi, xqlo, xkhi, xklo,
            Wqhi, Wqlo, Wkhi, Wklo, bq, bk, QT, KT);
        fftcorr_k<<<dim3(16, 32), 512, 0, stream>>>(QT, KT, Pf + (size_t)p * 32 * Ln);
    }
    ifftcorr_k<<<128, 512, 0, stream>>>(Pf, corr);
    topk_k<<<128, 256, 0, stream>>>(corr, topw, topi);
    agg_k<<<dim3(64, 128), 256, 0, stream>>>(Vstage, topw, topi, Y);
    gemm_o_k<<<dim3(256, 8), 256, 0, stream>>>(Y, Wof, bo, out);
}

// Round 21
// 1179.694 us; speedup vs baseline: 5.6841x; 1.0532x over previous
//
#include <hip/hip_runtime.h>

#define DEVI static __device__ __forceinline__

typedef float    f32x4 __attribute__((ext_vector_type(4)));
typedef _Float16 f16x8 __attribute__((ext_vector_type(8)));

static constexpr int Bn = 8, Ln = 4096, Dn = 1024, Hn = 16, DKn = 64;
static constexpr int TOPK = 8;
static constexpr float LO_SCALE = 2048.f, LO_INV = 1.f / 2048.f;

DEVI f32x4 mfma_f16(f16x8 a, f16x8 b, f32x4 c) {
    return __builtin_amdgcn_mfma_f32_16x16x32_f16(a, b, c, 0, 0, 0);
}

struct HL { _Float16 hi, lo; };
DEVI HL split2(float x) {
    HL r;
    r.hi = (_Float16)x;
    r.lo = (_Float16)((x - (float)r.hi) * LO_SCALE);
    return r;
}

DEVI void gload16(const void* g, void* l) {
    __builtin_amdgcn_global_load_lds(
        (const __attribute__((address_space(1))) unsigned int*)g,
        (__attribute__((address_space(3))) unsigned int*)l,
        16, 0, 0);
}

// ---------------------------------------------------------------------------
// conversion kernels (memory-bound)
// ---------------------------------------------------------------------------
__global__ __launch_bounds__(256) void cvt_split_k(
    const float* __restrict__ srcA, _Float16* __restrict__ hiA, _Float16* __restrict__ loA,
    const float* __restrict__ srcB, _Float16* __restrict__ hiB, _Float16* __restrict__ loB,
    int n8)
{
    const float* s  = blockIdx.y ? srcB : srcA;
    _Float16*    ph = blockIdx.y ? hiB  : hiA;
    _Float16*    pl = blockIdx.y ? loB  : loA;
    const int idx = blockIdx.x * 256 + threadIdx.x;
    if (idx >= n8) return;
    f32x4 x0 = *(const f32x4*)(s + (size_t)idx * 8);
    f32x4 x1 = *(const f32x4*)(s + (size_t)idx * 8 + 4);
    f16x8 h, l;
#pragma unroll
    for (int j = 0; j < 4; j++) {
        HL p0 = split2(x0[j]), p1 = split2(x1[j]);
        h[j] = p0.hi; l[j] = p0.lo;
        h[4 + j] = p1.hi; l[4 + j] = p1.lo;
    }
    *(f16x8*)(ph + (size_t)idx * 8) = h;
    *(f16x8*)(pl + (size_t)idx * 8) = l;
}

__global__ __launch_bounds__(256) void cvt_f16_k(
    const float* __restrict__ srcA, _Float16* __restrict__ dstA,
    const float* __restrict__ srcB, _Float16* __restrict__ dstB, int n8)
{
    const float* s = blockIdx.y ? srcB : srcA;
    _Float16*    d = blockIdx.y ? dstB : dstA;
    const int idx = blockIdx.x * 256 + threadIdx.x;
    if (idx >= n8) return;
    f32x4 x0 = *(const f32x4*)(s + (size_t)idx * 8);
    f32x4 x1 = *(const f32x4*)(s + (size_t)idx * 8 + 4);
    f16x8 o;
#pragma unroll
    for (int j = 0; j < 4; j++) { o[j] = (_Float16)x0[j]; o[4 + j] = (_Float16)x1[j]; }
    *(f16x8*)(d + (size_t)idx * 8) = o;
}

// ---------------------------------------------------------------------------
// Shared staging helpers (XOR-swizzled source; LDS dest linear; fragment
// reads XOR the same involution -- round-20: conflicts 8.4M -> 0).
// ---------------------------------------------------------------------------
DEVI void stage8(const _Float16* gbase, _Float16* ltile, int w, int lane, int k0) {
    const int gsrc = (lane & 3) ^ ((lane >> 3) & 3);   // g ^ ((row>>1)&3)
#pragma unroll
    for (int c = 0; c < 2; c++) {
        const int chunk = 2 * w + c;
        const int row = chunk * 16 + (lane >> 2);
        gload16(gbase + (size_t)row * Dn + k0 + gsrc * 8, ltile + chunk * 512);
    }
}

DEVI void stage16f32(const float* gbase, float* ltile, int w, int lane, int k0) {
    const int r    = lane >> 3;
    const int gsrc = (lane & 7) ^ r;
#pragma unroll
    for (int c = 0; c < 4; c++) {
        const int chunk = w * 4 + c;
        const int row = chunk * 8 + r;
        gload16(gbase + (size_t)row * Dn + k0 + gsrc * 4, ltile + chunk * 256);
    }
}

// ---------------------------------------------------------------------------
// m97-structure GEMM, plain variants (gemm_v / gemm_o) -- unchanged, proven.
// ---------------------------------------------------------------------------
template<int MODE, bool AF32>
DEVI void gemm4_body(
    const void* __restrict__ A_hi,
    const _Float16* __restrict__ W_hi,
    const float* __restrict__ bias, void* __restrict__ out0)
{
    constexpr int ASZ = AF32 ? 16384 : 8192;
    __shared__ char smem[ASZ + 8192];
    float*    sAf = (float*)smem;
    _Float16* sAh = (_Float16*)smem;
    _Float16* sWh = (_Float16*)(smem + ASZ);

    const int l  = threadIdx.x & 63;
    const int w  = threadIdx.x >> 6;
    const int m0 = blockIdx.x * 128;
    const int n0 = blockIdx.y * 128;
    const int wm = (w & 1) * 64, wn = (w >> 1) * 64;
    const int rr = l & 15, g0 = (l >> 4) * 2;
    const int gsw = (((l >> 4) ^ ((rr >> 1) & 3)) * 8);

    const _Float16* Wbh = W_hi + (size_t)n0 * Dn;

    f32x4 acc[4][4] = {};

    for (int k0 = 0; k0 < Dn; k0 += 32) {
        if (AF32) stage16f32((const float*)A_hi + (size_t)m0 * Dn, sAf, w, l, k0);
        else      stage8((const _Float16*)A_hi + (size_t)m0 * Dn, sAh, w, l, k0);
        stage8(Wbh, sWh, w, l, k0);
        __syncthreads();

        f16x8 af[4], bf[4];
#pragma unroll
        for (int i = 0; i < 4; i++) {
            const int arow = wm + 16 * i + rr;
            if (AF32) {
                const float* rb = &sAf[arow * 32];
                f32x4 x0 = *(const f32x4*)&rb[((g0    ) ^ (arow & 7)) * 4];
                f32x4 x1 = *(const f32x4*)&rb[((g0 + 1) ^ (arow & 7)) * 4];
#pragma unroll
                for (int j = 0; j < 4; j++) {
                    af[i][j]     = (_Float16)x0[j];
                    af[i][4 + j] = (_Float16)x1[j];
                }
            } else {
                af[i] = *(const f16x8*)&sAh[arow * 32 + gsw];
            }
            bf[i] = *(const f16x8*)&sWh[(wn + 16 * i + rr) * 32 + gsw];
        }
#pragma unroll
        for (int i = 0; i < 4; i++)
#pragma unroll
            for (int j = 0; j < 4; j++)
                acc[i][j] = mfma_f16(af[i], bf[j], acc[i][j]);
        __syncthreads();
    }

#pragma unroll
    for (int i = 0; i < 4; i++)
#pragma unroll
        for (int j = 0; j < 4; j++)
#pragma unroll
            for (int r = 0; r < 4; r++) {
                const int m = m0 + wm + 16 * i + (l >> 4) * 4 + r;
                const int n = n0 + wn + 16 * j + (l & 15);
                float v = acc[i][j][r] + bias[n];
                if (MODE == 0) {
                    ((float*)out0)[(size_t)m * Dn + n] = v;
                } else {
                    size_t idx = ((size_t)((m >> 12) * Hn + (n >> 6)) * Ln
                                  + (m & (Ln - 1))) * DKn + (n & 63);
                    ((_Float16*)out0)[idx] = (_Float16)v;
                }
            }
}

__global__ __launch_bounds__(256) void gemm_v_k(
    const float* __restrict__ xv, const _Float16* __restrict__ Wv,
    const float* __restrict__ bv, _Float16* __restrict__ Vstage)
{
    gemm4_body<1, true>(xv, Wv, bv, Vstage);
}

__global__ __launch_bounds__(256) void gemm_o_k(
    const _Float16* __restrict__ Y, const _Float16* __restrict__ Wo,
    const float* __restrict__ bo, float* __restrict__ out)
{
    gemm4_body<0, false>(Y, Wo, bo, out);
}

// ---------------------------------------------------------------------------
// COMP Q/K GEMM, v2: T3-minimum 2-phase DOUBLE-BUFFERED pipeline.
// Per k-step: stage(buf^1, k+32) issued BEFORE ds_read+MFMA(buf), then ONE
// __syncthreads (drains vmcnt after MFMA covered part of the latency).
// Barriers halve (64 -> 33); staging overlaps compute. LDS 2x32KB = 64KB
// -> 2 blocks/CU = 8 waves (>= measured 7 today, nothing lost).
// Epilogue: LDS-transpose, coalesced f32 [b2][n][l] stores (rule #20:
// j-loop fully unrolled).
// ---------------------------------------------------------------------------
DEVI void gemm_qk_body(
    const _Float16* __restrict__ A_hi, const _Float16* __restrict__ A_lo,
    const _Float16* __restrict__ W_hi, const _Float16* __restrict__ W_lo,
    const float* __restrict__ bias, float* __restrict__ out0)
{
    __shared__ _Float16 lds[2][4][4096];   // [buf][Ah,Al,Wh,Wl][128*32]

    const int l  = threadIdx.x & 63;
    const int w  = threadIdx.x >> 6;
    const int m0 = blockIdx.x * 128;
    const int n0 = blockIdx.y * 128;
    const int wm = (w & 1) * 64, wn = (w >> 1) * 64;
    const int rr = l & 15;
    const int gsw = (((l >> 4) ^ ((rr >> 1) & 3)) * 8);

    const _Float16* Abh = A_hi + (size_t)m0 * Dn;
    const _Float16* Abl = A_lo + (size_t)m0 * Dn;
    const _Float16* Wbh = W_hi + (size_t)n0 * Dn;
    const _Float16* Wbl = W_lo + (size_t)n0 * Dn;

    f32x4 acc[4][4] = {};
    f32x4 accc[4][4] = {};

    auto stage_all = [&](int buf, int k0) {
        stage8(Abh, &lds[buf][0][0], w, l, k0);
        stage8(Abl, &lds[buf][1][0], w, l, k0);
        stage8(Wbh, &lds[buf][2][0], w, l, k0);
        stage8(Wbl, &lds[buf][3][0], w, l, k0);
    };

    stage_all(0, 0);
    __syncthreads();

    int cur = 0;
    for (int k0 = 0; k0 < Dn; k0 += 32) {
        if (k0 + 32 < Dn) stage_all(cur ^ 1, k0 + 32);   // prefetch next tile

        const _Float16* sAh = &lds[cur][0][0];
        const _Float16* sAl = &lds[cur][1][0];
        const _Float16* sWh = &lds[cur][2][0];
        const _Float16* sWl = &lds[cur][3][0];
        f16x8 af[4], alf[4], bf[4], blf[4];
#pragma unroll
        for (int i = 0; i < 4; i++) {
            const int arow = wm + 16 * i + rr;
            const int wrow = wn + 16 * i + rr;
            af[i]  = *(const f16x8*)&sAh[arow * 32 + gsw];
            alf[i] = *(const f16x8*)&sAl[arow * 32 + gsw];
            bf[i]  = *(const f16x8*)&sWh[wrow * 32 + gsw];
            blf[i] = *(const f16x8*)&sWl[wrow * 32 + gsw];
        }
#pragma unroll
        for (int i = 0; i < 4; i++)
#pragma unroll
            for (int j = 0; j < 4; j++) {
                acc[i][j]  = mfma_f16(af[i],  bf[j],  acc[i][j]);
                accc[i][j] = mfma_f16(alf[i], bf[j],  accc[i][j]);
                accc[i][j] = mfma_f16(af[i],  blf[j], accc[i][j]);
            }
        __syncthreads();   // next tile staged & everyone done with cur
        cur ^= 1;
    }

    // LDS-transpose epilogue: coalesced stores to [b2][n][l] f32.
    float* sT = (float*)&lds[0][0][0];     // 32 x 132 f32 (16.9KB)
    const int b2 = m0 >> 12;
    const int mb = m0 & (Ln - 1);
    const int npr = (wn >> 6) * 16 + rr;
#pragma unroll
    for (int j = 0; j < 4; j++) {          // FULLY UNROLLED (rule #20)
        __syncthreads();
        const float bs = bias[n0 + wn + 16 * j + rr];
#pragma unroll
        for (int i = 0; i < 4; i++)
#pragma unroll
            for (int r = 0; r < 4; r++) {
                float v = acc[i][j][r] + accc[i][j][r] * LO_INV + bs;
                sT[npr * 132 + wm + 16 * i + (l >> 4) * 4 + r] = v;
            }
        __syncthreads();
        const int row = threadIdx.x >> 3;
        const int cb  = (threadIdx.x & 7) * 16;
        const int n   = n0 + (row >> 4) * 64 + 16 * j + (row & 15);
        float* dst = out0 + ((size_t)(b2 * 1024 + n)) * Ln + mb + cb;
        const float* sp = &sT[row * 132 + cb];
#pragma unroll
        for (int c4 = 0; c4 < 4; c4++)
            *(f32x4*)(dst + 4 * c4) = *(const f32x4*)(sp + 4 * c4);
    }
}

__global__ __launch_bounds__(256) void gemm_qk_k(
    const _Float16* __restrict__ xqhi, const _Float16* __restrict__ xqlo,
    const _Float16* __restrict__ xkhi, const _Float16* __restrict__ xklo,
    const _Float16* __restrict__ Wqhi, const _Float16* __restrict__ Wqlo,
    const _Float16* __restrict__ Wkhi, const _Float16* __restrict__ Wklo,
    const float* __restrict__ bq, const float* __restrict__ bk,
    float* __restrict__ QT, float* __restrict__ KT)
{
    if (blockIdx.z == 0)
        gemm_qk_body(xqhi, xqlo, Wqhi, Wqlo, bq, QT);
    else
        gemm_qk_body(xkhi, xklo, Wkhi, Wklo, bk, KT);
}

// ---------------------------------------------------------------------------
// FFT-based correlation (512 threads/block, two-reals pack, verified).
// ---------------------------------------------------------------------------
DEVI int FPAD(int i) { return i + (i >> 4) + (i >> 8); }

DEVI float2 cmulf(float2 a, float2 b) {
    return make_float2(a.x * b.x - a.y * b.y, a.x * b.y + a.y * b.x);
}

DEVI void fft_pass(const float2* in, float2* out, int ls2, int tid) {
    const int Ns = 1 << ls2;
#pragma unroll
    for (int r = 0; r < 2; r++) {
        const int j = tid + r * 512;
        float2 v0 = in[FPAD(j)];
        float2 v1 = in[FPAD(j + 1024)];
        float2 v2 = in[FPAD(j + 2048)];
        float2 v3 = in[FPAD(j + 3072)];
        const int p = j & (Ns - 1);
        const float ang = -6.283185307179586f * (float)p / (4.f * (float)Ns);
        float sn, cs;
        __sincosf(ang, &sn, &cs);
        const float2 w1 = make_float2(cs, sn);
        const float2 w2 = cmulf(w1, w1);
        const float2 w3 = cmulf(w2, w1);
        v1 = cmulf(v1, w1); v2 = cmulf(v2, w2); v3 = cmulf(v3, w3);
        const float2 t0 = make_float2(v0.x + v2.x, v0.y + v2.y);
        const float2 t1 = make_float2(v0.x - v2.x, v0.y - v2.y);
        const float2 t2 = make_float2(v1.x + v3.x, v1.y + v3.y);
        const float2 t3 = make_float2(v1.x - v3.x, v1.y - v3.y);
        const float2 t3i = make_float2(t3.y, -t3.x);
        const int db = ((j >> ls2) << (ls2 + 2)) | p;
        out[FPAD(db)]          = make_float2(t0.x + t2.x, t0.y + t2.y);
        out[FPAD(db + Ns)]     = make_float2(t1.x + t3i.x, t1.y + t3i.y);
        out[FPAD(db + 2 * Ns)] = make_float2(t0.x - t2.x, t0.y - t2.y);
        out[FPAD(db + 3 * Ns)] = make_float2(t1.x - t3i.x, t1.y - t3i.y);
    }
}

DEVI void fft4096(float2* A, float2* B, int tid) {
    __syncthreads();
    fft_pass(A, B, 0, tid);  __syncthreads();
    fft_pass(B, A, 2, tid);  __syncthreads();
    fft_pass(A, B, 4, tid);  __syncthreads();
    fft_pass(B, A, 6, tid);  __syncthreads();
    fft_pass(A, B, 8, tid);  __syncthreads();
    fft_pass(B, A, 10, tid); __syncthreads();
}

__global__ __launch_bounds__(512) void fftcorr_k(
    const float* __restrict__ QT, const float* __restrict__ KT,
    float2* __restrict__ Pf)
{
    __shared__ float2 A[4368], B[4368];
    const int tid = threadIdx.x;
    const int bh  = blockIdx.y;
    const int d0  = blockIdx.x * 4;
    float2 acc[8];
#pragma unroll
    for (int i = 0; i < 8; i++) acc[i] = make_float2(0.f, 0.f);

    for (int dd = 0; dd < 4; dd++) {
        const int d = d0 + dd;
        const float* qc = QT + ((size_t)bh * 64 + d) * Ln;
        const float* kc = KT + ((size_t)bh * 64 + d) * Ln;
#pragma unroll
        for (int i = 0; i < 8; i++) {
            const int row = tid + 512 * i;
            A[FPAD(row)] = make_float2(qc[row], kc[row]);
        }
        fft4096(A, B, tid);
#pragma unroll
        for (int i = 0; i < 8; i++) {
            const int t  = tid + 512 * i;
            const int tm = (Ln - t) & (Ln - 1);
            float2 Zt = A[FPAD(t)];
            float2 Zm = A[FPAD(tm)];
            const float qr = 0.5f * (Zt.x + Zm.x);
            const float qi = 0.5f * (Zt.y - Zm.y);
            const float kr = 0.5f * (Zt.y + Zm.y);
            const float ki = 0.5f * (Zm.x - Zt.x);
            acc[i].x += qr * kr + qi * ki;
            acc[i].y += qi * kr - qr * ki;
        }
        __syncthreads();
    }
    float2* P = Pf + (size_t)bh * Ln;
#pragma unroll
    for (int i = 0; i < 8; i++) {
        atomicAdd(&P[tid + 512 * i].x, acc[i].x);
        atomicAdd(&P[tid + 512 * i].y, acc[i].y);
    }
}

__global__ __launch_bounds__(512) void ifftcorr_k(
    const float2* __restrict__ Pf, float* __restrict__ corr)
{
    __shared__ float2 A[4368], B[4368];
    const int tid = threadIdx.x;
    const int bh = blockIdx.x;
    const float2* P = Pf + (size_t)bh * Ln;
#pragma unroll
    for (int i = 0; i < 8; i++) {
        float2 v = P[tid + 512 * i];
        A[FPAD(tid + 512 * i)] = make_float2(v.x, -v.y);
    }
    fft4096(A, B, tid);
#pragma unroll
    for (int i = 0; i < 8; i++)
        corr[(size_t)bh * Ln + tid + 512 * i] =
            A[FPAD(tid + 512 * i)].x * (1.f / 4096.f);
}

// ---------------------------------------------------------------------------
// Top-8 + softmax per (b,h) row of corr (raw sums; /64 before softmax).
// ---------------------------------------------------------------------------
__global__ __launch_bounds__(256) void topk_k(
    const float* __restrict__ corr, float* __restrict__ top_w,
    int* __restrict__ top_idx)
{
    __shared__ float vals[Ln];
    __shared__ float rv[256];
    __shared__ int   ri[256];
    __shared__ float sel_v[TOPK];
    __shared__ int   sel_i[TOPK];
    const int bh = blockIdx.x;
    const float* c = corr + (size_t)bh * Ln;
    for (int i = threadIdx.x; i < Ln; i += 256) vals[i] = c[i];
    __syncthreads();

    for (int it = 0; it < TOPK; it++) {
        float bvv = -1e30f; int bi = 0;
        const int base = threadIdx.x * 16;
#pragma unroll
        for (int j = 0; j < 16; j++) {
            float v = vals[base + j];
            if (v > bvv) { bvv = v; bi = base + j; }
        }
        rv[threadIdx.x] = bvv; ri[threadIdx.x] = bi;
        __syncthreads();
        if (threadIdx.x == 0) {
            float gv = rv[0]; int gi = ri[0];
            for (int t = 1; t < 256; t++)
                if (rv[t] > gv) { gv = rv[t]; gi = ri[t]; }
            sel_v[it] = gv; sel_i[it] = gi;
            vals[gi] = -1e30f;
        }
        __syncthreads();
    }
    if (threadIdx.x == 0) {
        float e[TOPK], s = 0.f;
        for (int i = 0; i < TOPK; i++) {
            e[i] = expf((sel_v[i] - sel_v[0]) * (1.f / 64.f));
            s += e[i];
        }
        for (int i = 0; i < TOPK; i++) {
            top_w[bh * TOPK + i]   = e[i] / s;
            top_idx[bh * TOPK + i] = sel_i[i];
        }
    }
}

// ---------------------------------------------------------------------------
// Aggregation: Y[b][t][h*64+d] = sum_i w_i * V[b][h][(t-idx_i)&4095][d]
// ---------------------------------------------------------------------------
__global__ __launch_bounds__(256) void agg_k(
    const _Float16* __restrict__ V /* [B][H][L][64] */,
    const float* __restrict__ top_w, const int* __restrict__ top_idx,
    _Float16* __restrict__ Y /* [B][L][1024] */)
{
    __shared__ float w_s[TOPK];
    __shared__ int   i_s[TOPK];
    const int bh   = blockIdx.y;
    const int b    = bh >> 4, h = bh & 15;
    const int tloc = threadIdx.x >> 2;
    const int c16  = (threadIdx.x & 3) * 16;
    const int t    = blockIdx.x * 64 + tloc;
    if (threadIdx.x < TOPK) {
        w_s[threadIdx.x] = top_w[bh * TOPK + threadIdx.x];
        i_s[threadIdx.x] = top_idx[bh * TOPK + threadIdx.x];
    }
    __syncthreads();

    const _Float16* Vb = V + (size_t)bh * Ln * DKn;
    float acc[16] = {};
#pragma unroll
    for (int i = 0; i < TOPK; i++) {
        const int src = (t - i_s[i]) & (Ln - 1);
        const _Float16* p = Vb + (size_t)src * DKn + c16;
        f16x8 v0 = *(const f16x8*)(p);
        f16x8 v1 = *(const f16x8*)(p + 8);
        const float wgt = w_s[i];
#pragma unroll
        for (int j = 0; j < 8; j++) acc[j]     += wgt * (float)v0[j];
#pragma unroll
        for (int j = 0; j < 8; j++) acc[8 + j] += wgt * (float)v1[j];
    }
    f16x8 o0, o1;
#pragma unroll
    for (int j = 0; j < 8; j++) { o0[j] = (_Float16)acc[j]; o1[j] = (_Float16)acc[8 + j]; }
    const size_t oidx = ((size_t)(b * Ln + t)) * Dn + h * DKn + c16;
    *(f16x8*)(Y + oidx)     = o0;
    *(f16x8*)(Y + oidx + 8) = o1;
}

// ---------------------------------------------------------------------------
extern "C" void kernel_launch(void* const* d_in, const int* in_sizes, int n_in,
                              void* d_out, int out_size, void* d_ws, size_t ws_size,
                              hipStream_t stream)
{
    const float* q  = (const float*)d_in[0];
    const float* kk = (const float*)d_in[1];
    const float* v  = (const float*)d_in[2];
    const float* Wq = (const float*)d_in[3];
    const float* bq = (const float*)d_in[4];
    const float* Wk = (const float*)d_in[5];
    const float* bk = (const float*)d_in[6];
    const float* Wv = (const float*)d_in[7];
    const float* bv = (const float*)d_in[8];
    const float* Wo = (const float*)d_in[9];
    const float* bo = (const float*)d_in[10];
    float* out = (float*)d_out;

    char* ws = (char*)d_ws;
    if (ws_size < 85991424ull) return;
    float*    QT   = (float*)(ws);
    float*    KT   = (float*)(ws + 33554432);
    _Float16* Y    = (_Float16*)(ws);
    float*    corr = (float*)(ws + 67108864);
    float*    topw = (float*)(ws + 69206016);
    int*      topi = (int*)(ws + 69210112);
    _Float16* Wqhi = (_Float16*)(ws + 69214208);
    _Float16* Wqlo = (_Float16*)(ws + 71311360);
    _Float16* Wkhi = (_Float16*)(ws + 73408512);
    _Float16* Wklo = (_Float16*)(ws + 75505664);
    _Float16* Wvf  = (_Float16*)(ws + 77602816);
    _Float16* Wof  = (_Float16*)(ws + 79699968);
    float2*   Pf   = (float2*)(ws + 81797120);

    _Float16* Vstage = (_Float16*)d_out;
    _Float16* xqhi = (_Float16*)((char*)d_out + 67108864);
    _Float16* xqlo = (_Float16*)((char*)d_out + 83886080);
    _Float16* xkhi = (_Float16*)((char*)d_out + 100663296);
    _Float16* xklo = (_Float16*)((char*)d_out + 117440512);

    (void)hipMemsetAsync(Pf, 0, (size_t)128 * Ln * sizeof(float2), stream);

    cvt_split_k<<<dim3(512, 2), 256, 0, stream>>>(Wq, Wqhi, Wqlo, Wk, Wkhi, Wklo, 131072);
    cvt_f16_k<<<dim3(512, 2), 256, 0, stream>>>(Wv, Wvf, Wo, Wof, 131072);

    gemm_v_k<<<dim3(256, 8), 256, 0, stream>>>(v, Wvf, bv, Vstage);

    for (int p = 0; p < 4; p++) {
        cvt_split_k<<<dim3(4096, 2), 256, 0, stream>>>(
            q + (size_t)p * 2 * Ln * Dn, xqhi, xqlo,
            kk + (size_t)p * 2 * Ln * Dn, xkhi, xklo, 1048576);
        gemm_qk_k<<<dim3(64, 8, 2), 256, 0, stream>>>(
            xqhi, xqlo, xkhi, xklo,
            Wqhi, Wqlo, Wkhi, Wklo, bq, bk, QT, KT);
        fftcorr_k<<<dim3(16, 32), 512, 0, stream>>>(QT, KT, Pf + (size_t)p * 32 * Ln);
    }
    ifftcorr_k<<<128, 512, 0, stream>>>(Pf, corr);
    topk_k<<<128, 256, 0, stream>>>(corr, topw, topi);
    agg_k<<<dim3(64, 128), 256, 0, stream>>>(Vstage, topw, topi, Y);
    gemm_o_k<<<dim3(256, 8), 256, 0, stream>>>(Y, Wof, bo, out);
}